// Round 11
// baseline (502.081 us; speedup 1.0000x reference)
//
#include <hip/hip_runtime.h>
#include <hip/hip_bf16.h>
#include <cmath>

// Problem constants (match reference setup_inputs)
#define NN    50000
#define EE    1600000
#define FIN   512
#define NHEAD 8
#define OUT1  8
#define HID   64      // NHEAD*OUT1
#define NCLS  7

#define NB    391     // ceil(NN/128) buckets of 128 nodes
#define EPB   4096    // edges per block in phase A
#define LOG2E 1.4426950408889634f
#define NPASS 4       // channel blocks of 16 (L2-resident 3.2MB sub-tables)

// ---------------------------------------------------------------------------
// Workspace layout (4-byte elements):
//   acc_eb  @ 0          N*64   blocked [4][N][16]  (tmp_r aliases during CSR
//                               build; gemm1 partial p0 before prop1)
//   s_j     @ 3,200,000  N*8    (pre-scaled by log2e)
//   sird    @ 3,600,000  N*8 float2  {s_i*log2e, 1/den}
//   dinv    @ 4,400,000  N
//   Binv    @ 4,450,000  N
//   xhb     @ 4,500,000  N*64   blocked [4][N][16]  (tmp_c aliases during build)
//   h       @ 7,700,000  N*64   (gemm1 partial p1, then h)
//   xh2     @ 10,900,000 N*8
//   acc_e2  @ 11,300,000 N*8
//   rptr    @ 11,700,000 N+1  int
//   cptr    @ 11,760,000 N+1  int
//   bh_r/bh_c/bs_r/bs_c/bc_r/bc_c @ 11,820,000 + k*1000
//   csr_row_c @ 11,830,000 E  int
//   csr_col_r @ 13,430,000 E  int
// ---------------------------------------------------------------------------
#define OFF_P0     0            // gemm1 partial p0 / later acc_eb
#define OFF_SJ     3200000
#define OFF_SIRD   3600000
#define OFF_DINV   4400000
#define OFF_BINV   4450000
#define OFF_XHB    4500000      // blocked xh
#define OFF_H      7700000      // gemm1 partial p1 / later h
#define OFF_XH2    10900000
#define OFF_ACCE2  11300000
#define OFF_RPTR   11700000
#define OFF_CPTR   11760000
#define OFF_BHR    11820000
#define OFF_BHC    11821000
#define OFF_BSR    11822000
#define OFF_BSC    11823000
#define OFF_BCR    11824000
#define OFF_BCC    11825000
#define OFF_CSRRC  11830000
#define OFF_CSRCR  13430000

#define LRELU(a) ((a) > 0.f ? (a) : 0.2f * (a))

__device__ __forceinline__ float fexp2(float x) {
#if __has_builtin(__builtin_amdgcn_exp2f)
  return __builtin_amdgcn_exp2f(x);
#else
  return exp2f(x);
#endif
}

// ---------------------------------------------------------------------------
__global__ __launch_bounds__(512) void zero_small(int* __restrict__ bh_r,
                                                  int* __restrict__ bh_c) {
  int t = threadIdx.x;
  if (t <= NB) { bh_r[t] = 0; bh_c[t] = 0; }
}

// ---------------------------------------------------------------------------
__global__ __launch_bounds__(256) void bucket_hist(const int* __restrict__ ei,
                                                   int* __restrict__ bh_r,
                                                   int* __restrict__ bh_c) {
  __shared__ int hr[NB], hc[NB];
  int t = threadIdx.x;
  for (int i = t; i < NB; i += 256) { hr[i] = 0; hc[i] = 0; }
  __syncthreads();
  for (int i = blockIdx.x * 256 + t; i < EE; i += gridDim.x * 256) {
    atomicAdd(hr + (ei[i] >> 7), 1);
    atomicAdd(hc + (ei[EE + i] >> 7), 1);
  }
  __syncthreads();
  for (int i = t; i < NB; i += 256) {
    if (hr[i]) atomicAdd(bh_r + i, hr[i]);
    if (hc[i]) atomicAdd(bh_c + i, hc[i]);
  }
}

// ---------------------------------------------------------------------------
__global__ __launch_bounds__(512) void bucket_scan(const int* __restrict__ bh_r,
                                                   const int* __restrict__ bh_c,
                                                   int* __restrict__ bs_r,
                                                   int* __restrict__ bs_c,
                                                   int* __restrict__ bc_r,
                                                   int* __restrict__ bc_c) {
  __shared__ int lds[512];
  int t = threadIdx.x;
  for (int side = 0; side < 2; ++side) {
    const int* bh = side ? bh_c : bh_r;
    int* bs = side ? bs_c : bs_r;
    int* bc = side ? bc_c : bc_r;
    int v = (t < NB) ? bh[t] : 0;
    lds[t] = v;
    __syncthreads();
    for (int off = 1; off < 512; off <<= 1) {
      int u = (t >= off) ? lds[t - off] : 0;
      __syncthreads();
      lds[t] += u;
      __syncthreads();
    }
    int excl = lds[t] - v;
    if (t <= NB) bs[t] = excl;
    if (t < NB) bc[t] = excl;
    __syncthreads();
  }
}

// ---------------------------------------------------------------------------
__global__ __launch_bounds__(256) void phaseA(const int* __restrict__ ei,
                                              int* __restrict__ bc_r,
                                              int* __restrict__ bc_c,
                                              int* __restrict__ tmp_r,
                                              int* __restrict__ tmp_c) {
  __shared__ int er[EPB];
  __shared__ int ec[EPB];
  __shared__ int hr[NB], hc[NB];
  const int e0 = blockIdx.x * EPB;
  const int cntE = min(EPB, EE - e0);
  const int t = threadIdx.x;
  for (int i = t; i < cntE; i += 256) { er[i] = ei[e0 + i]; ec[i] = ei[EE + e0 + i]; }
  for (int i = t; i < NB; i += 256) { hr[i] = 0; hc[i] = 0; }
  __syncthreads();
  for (int i = t; i < cntE; i += 256) {
    atomicAdd(hr + (er[i] >> 7), 1);
    atomicAdd(hc + (ec[i] >> 7), 1);
  }
  __syncthreads();
  for (int i = t; i < NB; i += 256) {
    int n = hr[i];
    hr[i] = n ? atomicAdd(bc_r + i, n) : 0;
    n = hc[i];
    hc[i] = n ? atomicAdd(bc_c + i, n) : 0;
  }
  __syncthreads();
  for (int i = t; i < cntE; i += 256) {
    int r = er[i], c = ec[i];
    int pr = atomicAdd(hr + (r >> 7), 1);
    tmp_r[pr] = ((r & 127) << 16) | c;
    int pc = atomicAdd(hc + (c >> 7), 1);
    tmp_c[pc] = ((c & 127) << 16) | r;
  }
}

// ---------------------------------------------------------------------------
__global__ __launch_bounds__(256) void phaseB(const int* __restrict__ tmp_r,
                                              const int* __restrict__ tmp_c,
                                              const int* __restrict__ bs_r,
                                              const int* __restrict__ bs_c,
                                              const float* __restrict__ hw,
                                              int* __restrict__ rptr,
                                              int* __restrict__ cptr,
                                              int* __restrict__ csr_row_c,
                                              int* __restrict__ csr_col_r,
                                              float* __restrict__ Binv) {
  const int side = blockIdx.x >= NB ? 1 : 0;
  const int b = blockIdx.x - side * NB;
  const int* tmp = side ? tmp_c : tmp_r;
  const int* bs = side ? bs_c : bs_r;
  int* ptr = side ? cptr : rptr;
  int* csr = side ? csr_col_r : csr_row_c;

  const int base = bs[b];
  const int M = bs[b + 1] - base;
  __shared__ int cnt[128], pre[128], cur[128];
  const int t = threadIdx.x;
  if (t < 128) cnt[t] = 0;
  __syncthreads();
  for (int i = t; i < M; i += 256) atomicAdd(cnt + (tmp[base + i] >> 16), 1);
  __syncthreads();
  if (t < 128) pre[t] = cnt[t];
  __syncthreads();
  for (int off = 1; off < 128; off <<= 1) {
    int u = (t >= off && t < 128) ? pre[t - off] : 0;
    __syncthreads();
    if (t < 128) pre[t] += u;
    __syncthreads();
  }
  const int node0 = b << 7;
  if (t < 128) {
    int excl = pre[t] - cnt[t];
    int g = node0 + t;
    if (g <= NN) ptr[g] = base + excl;
    cur[t] = base + excl;
    if (side && g < NN) Binv[g] = cnt[t] > 0 ? hw[g] / (float)cnt[t] : 0.f;
  }
  __syncthreads();
  for (int i = t; i < M; i += 256) {
    int e = tmp[base + i];
    int pos = atomicAdd(cur + (e >> 16), 1);
    csr[pos] = e & 0xFFFF;
  }
}

// ---------------------------------------------------------------------------
// GEMM1 split-K: blockIdx.y selects K-half and the output partial buffer.
__global__ __launch_bounds__(256) void gemm1_kernel(const float* __restrict__ x,
                                                    const float* __restrict__ W1,
                                                    float* __restrict__ p0,
                                                    float* __restrict__ p1) {
  __shared__ float lx[32][66];
  __shared__ float lw[32][68];
  const int t = threadIdx.x;
  const int row0 = blockIdx.x * 64;
  const int kbase = blockIdx.y * (FIN / 2);
  float* __restrict__ dst = blockIdx.y ? p1 : p0;
  const int ty = t >> 4, tx = t & 15;
  const int r0 = ty * 4, c0 = tx * 4;
  const int sr = t >> 2;
  const int sk = (t & 3) * 8;
  const int grow = row0 + sr;
  const int wk = t >> 3;
  const int wc = (t & 7) * 8;

  float acc[4][4] = {};

  for (int kb = kbase; kb < kbase + FIN / 2; kb += 32) {
    {
      float4 a0 = make_float4(0.f, 0.f, 0.f, 0.f), a1 = a0;
      if (grow < NN) {
        const float4* p = reinterpret_cast<const float4*>(x + (size_t)grow * FIN + kb + sk);
        a0 = p[0]; a1 = p[1];
      }
      lx[sk + 0][sr] = a0.x; lx[sk + 1][sr] = a0.y;
      lx[sk + 2][sr] = a0.z; lx[sk + 3][sr] = a0.w;
      lx[sk + 4][sr] = a1.x; lx[sk + 5][sr] = a1.y;
      lx[sk + 6][sr] = a1.z; lx[sk + 7][sr] = a1.w;
    }
    {
      const float4* q = reinterpret_cast<const float4*>(W1 + (size_t)(kb + wk) * HID + wc);
      float4 b0 = q[0], b1v = q[1];
      *reinterpret_cast<float4*>(&lw[wk][wc]) = b0;
      *reinterpret_cast<float4*>(&lw[wk][wc + 4]) = b1v;
    }
    __syncthreads();
#pragma unroll
    for (int kk = 0; kk < 32; ++kk) {
      const float4 af = *reinterpret_cast<const float4*>(&lx[kk][r0]);
      const float4 bf = *reinterpret_cast<const float4*>(&lw[kk][c0]);
      const float a4[4] = {af.x, af.y, af.z, af.w};
      const float b4[4] = {bf.x, bf.y, bf.z, bf.w};
#pragma unroll
      for (int i = 0; i < 4; ++i)
#pragma unroll
        for (int j = 0; j < 4; ++j)
          acc[i][j] = fmaf(a4[i], b4[j], acc[i][j]);
    }
    __syncthreads();
  }
#pragma unroll
  for (int i = 0; i < 4; ++i) {
    int gr = row0 + r0 + i;
    if (gr < NN) {
      float4 v = make_float4(acc[i][0], acc[i][1], acc[i][2], acc[i][3]);
      *reinterpret_cast<float4*>(dst + (size_t)gr * HID + c0) = v;
    }
  }
}

// ---------------------------------------------------------------------------
// Attention projections + split-K reduction.  Writes xh in CHANNEL-BLOCKED
// layout xhb[p][n][16] (p = hh>>1, offset (hh&1)*8) for the L2-resident
// prop passes.  sird.x = s_i*log2e, s_j = s_j*log2e.
__global__ __launch_bounds__(256) void attscore_kernel(const float* __restrict__ p0,
                                                       const float* __restrict__ p1,
                                                       const float* __restrict__ att1,
                                                       float* __restrict__ xhb,
                                                       float2* __restrict__ sird,
                                                       float* __restrict__ s_j) {
  int t = blockIdx.x * 256 + threadIdx.x;
  if (t >= NN * NHEAD) return;
  int n = t >> 3, hh = t & 7;
  const size_t base = (size_t)t * 8;
  float4 a0 = *reinterpret_cast<const float4*>(p0 + base);
  float4 a1 = *reinterpret_cast<const float4*>(p0 + base + 4);
  float4 q0 = *reinterpret_cast<const float4*>(p1 + base);
  float4 q1 = *reinterpret_cast<const float4*>(p1 + base + 4);
  float v[8] = {a0.x + q0.x, a0.y + q0.y, a0.z + q0.z, a0.w + q0.w,
                a1.x + q1.x, a1.y + q1.y, a1.z + q1.z, a1.w + q1.w};
  float si = 0.f, sj = 0.f;
#pragma unroll
  for (int c = 0; c < OUT1; ++c) {
    si = fmaf(v[c], att1[hh * 16 + c], si);
    sj = fmaf(v[c], att1[hh * 16 + 8 + c], sj);
  }
  float* dst = xhb + ((size_t)(hh >> 1) * NN + n) * 16 + (hh & 1) * 8;
  *reinterpret_cast<float4*>(dst)     = make_float4(v[0], v[1], v[2], v[3]);
  *reinterpret_cast<float4*>(dst + 4) = make_float4(v[4], v[5], v[6], v[7]);
  sird[t] = make_float2(si * LOG2E, 0.f);
  s_j[t] = sj * LOG2E;
}

// ---------------------------------------------------------------------------
// Softmax denominator (reciprocal -> sird.y) + node degree (Dinv) per row.
__global__ __launch_bounds__(256) void den_csr(const int* __restrict__ rptr,
                                               const int* __restrict__ csr_row_c,
                                               const float* __restrict__ s_j,
                                               const float* __restrict__ hw,
                                               float2* __restrict__ sird,
                                               float* __restrict__ dinv) {
  int wid = (blockIdx.x * 256 + threadIdx.x) >> 6;
  int lane = threadIdx.x & 63;
  if (wid >= NN) return;
  int r = wid;
  int hh = lane & 7;
  int eslot = lane >> 3;
  float si = sird[r * 8 + hh].x;
  int beg = rptr[r], end = rptr[r + 1];
  float aexp = 0.f, ad = 0.f;
  int i = beg + eslot;
  for (; i + 8 < end; i += 16) {
    int c0 = csr_row_c[i], c1 = csr_row_c[i + 8];
    float sj0 = s_j[c0 * 8 + hh], sj1 = s_j[c1 * 8 + hh];
    float h0 = hw[c0], h1 = hw[c1];
    float a0 = LRELU(si + sj0), a1 = LRELU(si + sj1);
    aexp += fexp2(a0) + fexp2(a1);
    ad += h0 + h1;
  }
  if (i < end) {
    int c = csr_row_c[i];
    float a = LRELU(si + s_j[c * 8 + hh]);
    aexp += fexp2(a);
    ad += hw[c];
  }
  aexp += __shfl_xor(aexp, 8);
  aexp += __shfl_xor(aexp, 16);
  aexp += __shfl_xor(aexp, 32);
  ad += __shfl_xor(ad, 8);
  ad += __shfl_xor(ad, 16);
  ad += __shfl_xor(ad, 32);
  if (eslot == 0) {
    reinterpret_cast<float*>(sird)[(r * 8 + hh) * 2 + 1] = 1.0f / (aexp + 1e-16f);
    if (hh == 0) dinv[r] = ad > 0.f ? 1.0f / ad : 0.f;
  }
}

// ---------------------------------------------------------------------------
// Propagate 1, channel-blocked pass p: wave = [4 edge-slots][16 channels].
// Gathers ONLY from the 3.2MB sub-table xhp = xhb + p*N*16 (L2-resident).
// head = 2p + (ch>>3); alpha is lane-local (no shuffles).
__global__ __launch_bounds__(256) void prop1_split(const int* __restrict__ cptr,
                                                   const int* __restrict__ csr_col_r,
                                                   const float* __restrict__ xhp,
                                                   const float2* __restrict__ sird,
                                                   const float* __restrict__ s_j,
                                                   const float* __restrict__ Binv,
                                                   float* __restrict__ acc_ep,
                                                   int p) {
  int wid = (blockIdx.x * 256 + threadIdx.x) >> 6;
  int lane = threadIdx.x & 63;
  if (wid >= NN) return;
  const int c = wid;
  const int g = lane >> 4;        // edge slot 0..3
  const int ch = lane & 15;       // channel within block
  const int head = 2 * p + (ch >> 3);
  const float sj = s_j[c * 8 + head];
  int beg = cptr[c], end = cptr[c + 1];
  float acc = 0.f;
  int i = beg;
  for (; i + 8 <= end; i += 8) {
    int r0 = csr_col_r[i + g];
    int r1 = csr_col_r[i + 4 + g];
    float2 q0 = sird[r0 * 8 + head];
    float2 q1 = sird[r1 * 8 + head];
    float v0 = xhp[(r0 << 4) + ch];
    float v1 = xhp[(r1 << 4) + ch];
    float al0 = fexp2(LRELU(q0.x + sj)) * q0.y;
    float al1 = fexp2(LRELU(q1.x + sj)) * q1.y;
    acc = fmaf(v0, al0, acc);
    acc = fmaf(v1, al1, acc);
  }
  for (; i + 4 <= end; i += 4) {
    int r = csr_col_r[i + g];
    float2 q = sird[r * 8 + head];
    float v = xhp[(r << 4) + ch];
    acc = fmaf(v, fexp2(LRELU(q.x + sj)) * q.y, acc);
  }
  if (i + g < end) {
    int r = csr_col_r[i + g];
    float2 q = sird[r * 8 + head];
    float v = xhp[(r << 4) + ch];
    acc = fmaf(v, fexp2(LRELU(q.x + sj)) * q.y, acc);
  }
  // sum the 4 edge-slot partials (lanes ch, ch+16, ch+32, ch+48)
  acc += __shfl_xor(acc, 16);
  acc += __shfl_xor(acc, 32);
  if (g == 0) acc_ep[(c << 4) + ch] = acc * Binv[c];
}

// ---------------------------------------------------------------------------
// Propagate 2 + finish1, channel-blocked pass p: gathers only from the 3.2MB
// sub-table acc_ep = acc_eb + p*N*16.  Writes h columns [16p, 16p+16).
__global__ __launch_bounds__(256) void prop2_split(const int* __restrict__ rptr,
                                                   const int* __restrict__ csr_row_c,
                                                   const float* __restrict__ acc_ep,
                                                   const float2* __restrict__ sird,
                                                   const float* __restrict__ s_j,
                                                   const float* __restrict__ dinv,
                                                   const float* __restrict__ b1,
                                                   float* __restrict__ h,
                                                   int p) {
  int wid = (blockIdx.x * 256 + threadIdx.x) >> 6;
  int lane = threadIdx.x & 63;
  if (wid >= NN) return;
  const int r = wid;
  const int g = lane >> 4;
  const int ch = lane & 15;
  const int head = 2 * p + (ch >> 3);
  float2 sr = sird[r * 8 + head];
  const float si = sr.x, rd = sr.y;
  int beg = rptr[r], end = rptr[r + 1];
  float acc = 0.f;
  int i = beg;
  for (; i + 8 <= end; i += 8) {
    int c0 = csr_row_c[i + g];
    int c1 = csr_row_c[i + 4 + g];
    float sj0 = s_j[c0 * 8 + head];
    float sj1 = s_j[c1 * 8 + head];
    float v0 = acc_ep[(c0 << 4) + ch];
    float v1 = acc_ep[(c1 << 4) + ch];
    acc = fmaf(v0, fexp2(LRELU(si + sj0)), acc);
    acc = fmaf(v1, fexp2(LRELU(si + sj1)), acc);
  }
  for (; i + 4 <= end; i += 4) {
    int cc = csr_row_c[i + g];
    float v = acc_ep[(cc << 4) + ch];
    acc = fmaf(v, fexp2(LRELU(si + s_j[cc * 8 + head])), acc);
  }
  if (i + g < end) {
    int cc = csr_row_c[i + g];
    float v = acc_ep[(cc << 4) + ch];
    acc = fmaf(v, fexp2(LRELU(si + s_j[cc * 8 + head])), acc);
  }
  acc += __shfl_xor(acc, 16);
  acc += __shfl_xor(acc, 32);
  if (g == 0) {
    float val = fmaf(acc * rd, dinv[r], b1[16 * p + ch]);
    h[(r << 6) + 16 * p + ch] = val > 0.f ? val : expm1f(val);
  }
}

// ---------------------------------------------------------------------------
// GEMM2: xh2[n,k] = sum_c h[n,c]*W2[c,k]  (k<7; slot 7 zeroed)
__global__ __launch_bounds__(256) void gemm2_kernel(const float* __restrict__ h,
                                                    const float* __restrict__ W2,
                                                    float* __restrict__ xh2) {
  int t = blockIdx.x * 256 + threadIdx.x;
  if (t >= NN * 8) return;
  int n = t >> 3, k = t & 7;
  if (k == 7) { xh2[t] = 0.f; return; }
  const float* hp = h + (size_t)n * HID;
  float acc = 0.f;
#pragma unroll
  for (int c = 0; c < HID; ++c) acc = fmaf(hp[c], W2[c * NCLS + k], acc);
  xh2[t] = acc;
}

// ---------------------------------------------------------------------------
// Layer-2 propagate 1: acc_e2[g] = Binv[g] * sum_r xh2[r]
__global__ __launch_bounds__(256) void prop3_csr(const int* __restrict__ cptr,
                                                 const int* __restrict__ csr_col_r,
                                                 const float* __restrict__ xh2,
                                                 const float* __restrict__ Binv,
                                                 float* __restrict__ acc_e2) {
  int t = blockIdx.x * 256 + threadIdx.x;
  int g = t >> 3, k = t & 7;
  if (g >= NN) return;
  int beg = cptr[g], end = cptr[g + 1];
  float acc = 0.f;
  int i = beg;
  for (; i + 3 < end; i += 4) {
    int r0 = csr_col_r[i], r1 = csr_col_r[i + 1];
    int r2 = csr_col_r[i + 2], r3 = csr_col_r[i + 3];
    float v0 = xh2[r0 * 8 + k], v1 = xh2[r1 * 8 + k];
    float v2 = xh2[r2 * 8 + k], v3 = xh2[r3 * 8 + k];
    acc += (v0 + v1) + (v2 + v3);
  }
  for (; i < end; ++i) acc += xh2[csr_col_r[i] * 8 + k];
  acc_e2[g * 8 + k] = acc * Binv[g];
}

// ---------------------------------------------------------------------------
// Layer-2 propagate 2 + log_softmax: 8 lanes per node.
__global__ __launch_bounds__(256) void prop4_csr(const int* __restrict__ rptr,
                                                 const int* __restrict__ csr_row_c,
                                                 const float* __restrict__ acc_e2,
                                                 const float* __restrict__ dinv,
                                                 const float* __restrict__ b2,
                                                 float* __restrict__ out) {
  int t = blockIdx.x * 256 + threadIdx.x;
  int r = t >> 3, k = t & 7;
  if (r >= NN) return;
  int beg = rptr[r], end = rptr[r + 1];
  float acc = 0.f;
  int i = beg;
  for (; i + 3 < end; i += 4) {
    int c0 = csr_row_c[i], c1 = csr_row_c[i + 1];
    int c2 = csr_row_c[i + 2], c3 = csr_row_c[i + 3];
    float v0 = acc_e2[c0 * 8 + k], v1 = acc_e2[c1 * 8 + k];
    float v2 = acc_e2[c2 * 8 + k], v3 = acc_e2[c3 * 8 + k];
    acc += (v0 + v1) + (v2 + v3);
  }
  for (; i < end; ++i) acc += acc_e2[csr_row_c[i] * 8 + k];
  float v = (k < NCLS) ? fmaf(acc, dinv[r], b2[k]) : -INFINITY;
  float m = v;
  m = fmaxf(m, __shfl_xor(m, 1, 8));
  m = fmaxf(m, __shfl_xor(m, 2, 8));
  m = fmaxf(m, __shfl_xor(m, 4, 8));
  float ex = (k < NCLS) ? expf(v - m) : 0.f;
  float s = ex;
  s += __shfl_xor(s, 1, 8);
  s += __shfl_xor(s, 2, 8);
  s += __shfl_xor(s, 4, 8);
  float lse = m + logf(s);
  if (k < NCLS) out[(size_t)r * NCLS + k] = v - lse;
}

// ---------------------------------------------------------------------------
extern "C" void kernel_launch(void* const* d_in, const int* in_sizes, int n_in,
                              void* d_out, int out_size, void* d_ws, size_t ws_size,
                              hipStream_t stream) {
  const float* x    = (const float*)d_in[0];
  const int*   ei   = (const int*)d_in[1];
  const float* hw   = (const float*)d_in[2];
  const float* W1   = (const float*)d_in[3];
  const float* att1 = (const float*)d_in[4];
  const float* b1   = (const float*)d_in[5];
  const float* W2   = (const float*)d_in[6];
  const float* b2   = (const float*)d_in[7];
  float* out = (float*)d_out;
  float* ws  = (float*)d_ws;

  float* p0buf  = ws + OFF_P0;     // gemm1 partial p0, later acc_eb (blocked)
  float* s_j    = ws + OFF_SJ;
  float2* sird  = (float2*)(ws + OFF_SIRD);
  float* dinv   = ws + OFF_DINV;
  float* Binv   = ws + OFF_BINV;
  float* xhb    = ws + OFF_XHB;    // blocked xh [4][N][16]
  float* hbuf   = ws + OFF_H;      // gemm1 partial p1, later h
  float* xh2    = ws + OFF_XH2;
  float* acc_e2 = ws + OFF_ACCE2;
  int* rptr = (int*)(ws + OFF_RPTR);
  int* cptr = (int*)(ws + OFF_CPTR);
  int* bh_r = (int*)(ws + OFF_BHR);
  int* bh_c = (int*)(ws + OFF_BHC);
  int* bs_r = (int*)(ws + OFF_BSR);
  int* bs_c = (int*)(ws + OFF_BSC);
  int* bc_r = (int*)(ws + OFF_BCR);
  int* bc_c = (int*)(ws + OFF_BCC);
  int* csr_row_c = (int*)(ws + OFF_CSRRC);
  int* csr_col_r = (int*)(ws + OFF_CSRCR);
  int* tmp_r = (int*)(ws + OFF_P0);   // aliases p0 region (consumed pre-gemm1)
  int* tmp_c = (int*)(ws + OFF_XHB);  // aliases xhb (consumed pre-attscore)

  // --- CSR build (bucketed counting sort, both orderings) ---
  zero_small<<<1, 512, 0, stream>>>(bh_r, bh_c);
  bucket_hist<<<256, 256, 0, stream>>>(ei, bh_r, bh_c);
  bucket_scan<<<1, 512, 0, stream>>>(bh_r, bh_c, bs_r, bs_c, bc_r, bc_c);
  phaseA<<<(EE + EPB - 1) / EPB, 256, 0, stream>>>(ei, bc_r, bc_c, tmp_r, tmp_c);
  phaseB<<<2 * NB, 256, 0, stream>>>(tmp_r, tmp_c, bs_r, bs_c, hw,
                                     rptr, cptr, csr_row_c, csr_col_r, Binv);

  // --- Layer 1 ---
  {
    dim3 g((NN + 63) / 64, 2);
    gemm1_kernel<<<g, 256, 0, stream>>>(x, W1, p0buf, hbuf);
  }
  attscore_kernel<<<(NN * NHEAD + 255) / 256, 256, 0, stream>>>(p0buf, hbuf, att1,
                                                                xhb, sird, s_j);
  den_csr<<<(NN * 64 + 255) / 256, 256, 0, stream>>>(rptr, csr_row_c, s_j, hw, sird, dinv);

  const int pgrid = (NN * 64 + 255) / 256;
  float* acc_eb = p0buf;  // blocked [4][N][16], overwrites p0 (no longer needed)
  for (int p = 0; p < NPASS; ++p)
    prop1_split<<<pgrid, 256, 0, stream>>>(cptr, csr_col_r,
                                           xhb + (size_t)p * NN * 16,
                                           sird, s_j, Binv,
                                           acc_eb + (size_t)p * NN * 16, p);
  for (int p = 0; p < NPASS; ++p)
    prop2_split<<<pgrid, 256, 0, stream>>>(rptr, csr_row_c,
                                           acc_eb + (size_t)p * NN * 16,
                                           sird, s_j, dinv, b1, hbuf, p);

  // --- Layer 2 ---
  gemm2_kernel<<<(NN * 8 + 255) / 256, 256, 0, stream>>>(hbuf, W2, xh2);
  prop3_csr<<<(NN * 8 + 255) / 256, 256, 0, stream>>>(cptr, csr_col_r, xh2, Binv, acc_e2);
  prop4_csr<<<(NN * 8 + 255) / 256, 256, 0, stream>>>(rptr, csr_row_c, acc_e2, dinv, b2, out);
}

// Round 12
// 344.534 us; speedup vs baseline: 1.4573x; 1.4573x over previous
//
#include <hip/hip_runtime.h>
#include <hip/hip_bf16.h>
#include <cmath>

// Problem constants (match reference setup_inputs)
#define NN    50000
#define EE    1600000
#define FIN   512
#define NHEAD 8
#define OUT1  8
#define HID   64      // NHEAD*OUT1
#define NCLS  7

#define NB    391     // ceil(NN/128) buckets of 128 nodes
#define EPB   4096    // edges per block in phase A
#define LOG2E 1.4426950408889634f

// ---------------------------------------------------------------------------
// Workspace layout (4-byte elements):
//   xh      @ 0          N*64   (tmp_r aliases during CSR build; gemm1 p0)
//   s_j     @ 3,200,000  N*8    (pre-scaled by log2e)
//   sird    @ 3,600,000  N*8 float2  {s_i*log2e, 1/den}
//   dinv    @ 4,400,000  N
//   Binv    @ 4,450,000  N
//   acc_e   @ 4,500,000  N*64   (tmp_c aliases during CSR build)
//   h       @ 7,700,000  N*64   (gemm1 partial p1 before prop2 writes h)
//   xh2     @ 10,900,000 N*8
//   acc_e2  @ 11,300,000 N*8
//   rptr    @ 11,700,000 N+1  int
//   cptr    @ 11,760,000 N+1  int
//   bh_r/bh_c/bs_r/bs_c/bc_r/bc_c @ 11,820,000 + k*1000
//   csr_row_c @ 11,830,000 E  ushort (E/2 ints)
//   csr_col_r @ 12,700,000 E  ushort (E/2 ints)
// ---------------------------------------------------------------------------
#define OFF_XH     0
#define OFF_SJ     3200000
#define OFF_SIRD   3600000
#define OFF_DINV   4400000
#define OFF_BINV   4450000
#define OFF_ACCE   4500000
#define OFF_H      7700000
#define OFF_XH2    10900000
#define OFF_ACCE2  11300000
#define OFF_RPTR   11700000
#define OFF_CPTR   11760000
#define OFF_BHR    11820000
#define OFF_BHC    11821000
#define OFF_BSR    11822000
#define OFF_BSC    11823000
#define OFF_BCR    11824000
#define OFF_BCC    11825000
#define OFF_CSRRC  11830000
#define OFF_CSRCR  12700000

#define LRELU(a) ((a) > 0.f ? (a) : 0.2f * (a))

__device__ __forceinline__ float fexp2(float x) {
#if __has_builtin(__builtin_amdgcn_exp2f)
  return __builtin_amdgcn_exp2f(x);
#else
  return exp2f(x);
#endif
}

// ---------------------------------------------------------------------------
__global__ __launch_bounds__(512) void zero_small(int* __restrict__ bh_r,
                                                  int* __restrict__ bh_c) {
  int t = threadIdx.x;
  if (t <= NB) { bh_r[t] = 0; bh_c[t] = 0; }
}

// ---------------------------------------------------------------------------
__global__ __launch_bounds__(256) void bucket_hist(const int* __restrict__ ei,
                                                   int* __restrict__ bh_r,
                                                   int* __restrict__ bh_c) {
  __shared__ int hr[NB], hc[NB];
  int t = threadIdx.x;
  for (int i = t; i < NB; i += 256) { hr[i] = 0; hc[i] = 0; }
  __syncthreads();
  for (int i = blockIdx.x * 256 + t; i < EE; i += gridDim.x * 256) {
    atomicAdd(hr + (ei[i] >> 7), 1);
    atomicAdd(hc + (ei[EE + i] >> 7), 1);
  }
  __syncthreads();
  for (int i = t; i < NB; i += 256) {
    if (hr[i]) atomicAdd(bh_r + i, hr[i]);
    if (hc[i]) atomicAdd(bh_c + i, hc[i]);
  }
}

// ---------------------------------------------------------------------------
__global__ __launch_bounds__(512) void bucket_scan(const int* __restrict__ bh_r,
                                                   const int* __restrict__ bh_c,
                                                   int* __restrict__ bs_r,
                                                   int* __restrict__ bs_c,
                                                   int* __restrict__ bc_r,
                                                   int* __restrict__ bc_c) {
  __shared__ int lds[512];
  int t = threadIdx.x;
  for (int side = 0; side < 2; ++side) {
    const int* bh = side ? bh_c : bh_r;
    int* bs = side ? bs_c : bs_r;
    int* bc = side ? bc_c : bc_r;
    int v = (t < NB) ? bh[t] : 0;
    lds[t] = v;
    __syncthreads();
    for (int off = 1; off < 512; off <<= 1) {
      int u = (t >= off) ? lds[t - off] : 0;
      __syncthreads();
      lds[t] += u;
      __syncthreads();
    }
    int excl = lds[t] - v;
    if (t <= NB) bs[t] = excl;
    if (t < NB) bc[t] = excl;
    __syncthreads();
  }
}

// ---------------------------------------------------------------------------
__global__ __launch_bounds__(256) void phaseA(const int* __restrict__ ei,
                                              int* __restrict__ bc_r,
                                              int* __restrict__ bc_c,
                                              int* __restrict__ tmp_r,
                                              int* __restrict__ tmp_c) {
  __shared__ int er[EPB];
  __shared__ int ec[EPB];
  __shared__ int hr[NB], hc[NB];
  const int e0 = blockIdx.x * EPB;
  const int cntE = min(EPB, EE - e0);
  const int t = threadIdx.x;
  for (int i = t; i < cntE; i += 256) { er[i] = ei[e0 + i]; ec[i] = ei[EE + e0 + i]; }
  for (int i = t; i < NB; i += 256) { hr[i] = 0; hc[i] = 0; }
  __syncthreads();
  for (int i = t; i < cntE; i += 256) {
    atomicAdd(hr + (er[i] >> 7), 1);
    atomicAdd(hc + (ec[i] >> 7), 1);
  }
  __syncthreads();
  for (int i = t; i < NB; i += 256) {
    int n = hr[i];
    hr[i] = n ? atomicAdd(bc_r + i, n) : 0;
    n = hc[i];
    hc[i] = n ? atomicAdd(bc_c + i, n) : 0;
  }
  __syncthreads();
  for (int i = t; i < cntE; i += 256) {
    int r = er[i], c = ec[i];
    int pr = atomicAdd(hr + (r >> 7), 1);
    tmp_r[pr] = ((r & 127) << 16) | c;
    int pc = atomicAdd(hc + (c >> 7), 1);
    tmp_c[pc] = ((c & 127) << 16) | r;
  }
}

// ---------------------------------------------------------------------------
// Phase B: one block per (side, bucket).  Emits 16-bit CSR entries.
// Row side additionally accumulates D = sum hw[col] per node via LDS float
// atomics and writes dinv (removing that work from den_csr).
__global__ __launch_bounds__(256) void phaseB(const int* __restrict__ tmp_r,
                                              const int* __restrict__ tmp_c,
                                              const int* __restrict__ bs_r,
                                              const int* __restrict__ bs_c,
                                              const float* __restrict__ hw,
                                              int* __restrict__ rptr,
                                              int* __restrict__ cptr,
                                              unsigned short* __restrict__ csr_row_c,
                                              unsigned short* __restrict__ csr_col_r,
                                              float* __restrict__ Binv,
                                              float* __restrict__ dinv) {
  const int side = blockIdx.x >= NB ? 1 : 0;
  const int b = blockIdx.x - side * NB;
  const int* tmp = side ? tmp_c : tmp_r;
  const int* bs = side ? bs_c : bs_r;
  int* ptr = side ? cptr : rptr;
  unsigned short* csr = side ? csr_col_r : csr_row_c;

  const int base = bs[b];
  const int M = bs[b + 1] - base;
  __shared__ int cnt[128], pre[128], cur[128];
  __shared__ float ds[128];
  const int t = threadIdx.x;
  if (t < 128) { cnt[t] = 0; ds[t] = 0.f; }
  __syncthreads();
  for (int i = t; i < M; i += 256) atomicAdd(cnt + (tmp[base + i] >> 16), 1);
  __syncthreads();
  if (t < 128) pre[t] = cnt[t];
  __syncthreads();
  for (int off = 1; off < 128; off <<= 1) {
    int u = (t >= off && t < 128) ? pre[t - off] : 0;
    __syncthreads();
    if (t < 128) pre[t] += u;
    __syncthreads();
  }
  const int node0 = b << 7;
  if (t < 128) {
    int excl = pre[t] - cnt[t];
    int g = node0 + t;
    if (g <= NN) ptr[g] = base + excl;
    cur[t] = base + excl;
    if (side && g < NN) Binv[g] = cnt[t] > 0 ? hw[g] / (float)cnt[t] : 0.f;
  }
  __syncthreads();
  for (int i = t; i < M; i += 256) {
    int e = tmp[base + i];
    int own = e >> 16;
    int other = e & 0xFFFF;
    int pos = atomicAdd(cur + own, 1);
    csr[pos] = (unsigned short)other;
    if (!side) atomicAdd(ds + own, hw[other]);
  }
  __syncthreads();
  if (!side && t < 128) {
    int g = node0 + t;
    if (g < NN) dinv[g] = ds[t] > 0.f ? 1.0f / ds[t] : 0.f;
  }
}

// ---------------------------------------------------------------------------
// GEMM1 split-K: blockIdx.y selects K-half and the output partial buffer.
__global__ __launch_bounds__(256) void gemm1_kernel(const float* __restrict__ x,
                                                    const float* __restrict__ W1,
                                                    float* __restrict__ p0,
                                                    float* __restrict__ p1) {
  __shared__ float lx[32][66];
  __shared__ float lw[32][68];
  const int t = threadIdx.x;
  const int row0 = blockIdx.x * 64;
  const int kbase = blockIdx.y * (FIN / 2);
  float* __restrict__ dst = blockIdx.y ? p1 : p0;
  const int ty = t >> 4, tx = t & 15;
  const int r0 = ty * 4, c0 = tx * 4;
  const int sr = t >> 2;
  const int sk = (t & 3) * 8;
  const int grow = row0 + sr;
  const int wk = t >> 3;
  const int wc = (t & 7) * 8;

  float acc[4][4] = {};

  for (int kb = kbase; kb < kbase + FIN / 2; kb += 32) {
    {
      float4 a0 = make_float4(0.f, 0.f, 0.f, 0.f), a1 = a0;
      if (grow < NN) {
        const float4* p = reinterpret_cast<const float4*>(x + (size_t)grow * FIN + kb + sk);
        a0 = p[0]; a1 = p[1];
      }
      lx[sk + 0][sr] = a0.x; lx[sk + 1][sr] = a0.y;
      lx[sk + 2][sr] = a0.z; lx[sk + 3][sr] = a0.w;
      lx[sk + 4][sr] = a1.x; lx[sk + 5][sr] = a1.y;
      lx[sk + 6][sr] = a1.z; lx[sk + 7][sr] = a1.w;
    }
    {
      const float4* q = reinterpret_cast<const float4*>(W1 + (size_t)(kb + wk) * HID + wc);
      float4 b0 = q[0], b1v = q[1];
      *reinterpret_cast<float4*>(&lw[wk][wc]) = b0;
      *reinterpret_cast<float4*>(&lw[wk][wc + 4]) = b1v;
    }
    __syncthreads();
#pragma unroll
    for (int kk = 0; kk < 32; ++kk) {
      const float4 af = *reinterpret_cast<const float4*>(&lx[kk][r0]);
      const float4 bf = *reinterpret_cast<const float4*>(&lw[kk][c0]);
      const float a4[4] = {af.x, af.y, af.z, af.w};
      const float b4[4] = {bf.x, bf.y, bf.z, bf.w};
#pragma unroll
      for (int i = 0; i < 4; ++i)
#pragma unroll
        for (int j = 0; j < 4; ++j)
          acc[i][j] = fmaf(a4[i], b4[j], acc[i][j]);
    }
    __syncthreads();
  }
#pragma unroll
  for (int i = 0; i < 4; ++i) {
    int gr = row0 + r0 + i;
    if (gr < NN) {
      float4 v = make_float4(acc[i][0], acc[i][1], acc[i][2], acc[i][3]);
      *reinterpret_cast<float4*>(dst + (size_t)gr * HID + c0) = v;
    }
  }
}

// ---------------------------------------------------------------------------
// Attention projections + split-K reduction: xh = p0 + p1 (in-place into p0),
// sird.x = s_i*log2e, s_j = s_j*log2e.
__global__ __launch_bounds__(256) void attscore_kernel(float* __restrict__ xh,
                                                       const float* __restrict__ p1,
                                                       const float* __restrict__ att1,
                                                       float2* __restrict__ sird,
                                                       float* __restrict__ s_j) {
  int t = blockIdx.x * 256 + threadIdx.x;
  if (t >= NN * NHEAD) return;
  int hh = t & 7;
  const size_t base = (size_t)t * 8;
  float4 a0 = *reinterpret_cast<const float4*>(xh + base);
  float4 a1 = *reinterpret_cast<const float4*>(xh + base + 4);
  float4 q0 = *reinterpret_cast<const float4*>(p1 + base);
  float4 q1 = *reinterpret_cast<const float4*>(p1 + base + 4);
  float v[8] = {a0.x + q0.x, a0.y + q0.y, a0.z + q0.z, a0.w + q0.w,
                a1.x + q1.x, a1.y + q1.y, a1.z + q1.z, a1.w + q1.w};
  float si = 0.f, sj = 0.f;
#pragma unroll
  for (int c = 0; c < OUT1; ++c) {
    si = fmaf(v[c], att1[hh * 16 + c], si);
    sj = fmaf(v[c], att1[hh * 16 + 8 + c], sj);
  }
  *reinterpret_cast<float4*>(xh + base)     = make_float4(v[0], v[1], v[2], v[3]);
  *reinterpret_cast<float4*>(xh + base + 4) = make_float4(v[4], v[5], v[6], v[7]);
  sird[t] = make_float2(si * LOG2E, 0.f);
  s_j[t] = sj * LOG2E;
}

// ---------------------------------------------------------------------------
// Softmax denominator (reciprocal -> sird.y).  D/dinv moved to phaseB.
__global__ __launch_bounds__(256) void den_csr(const int* __restrict__ rptr,
                                               const unsigned short* __restrict__ csr_row_c,
                                               const float* __restrict__ s_j,
                                               float2* __restrict__ sird) {
  int wid = (blockIdx.x * 256 + threadIdx.x) >> 6;
  int lane = threadIdx.x & 63;
  if (wid >= NN) return;
  int r = wid;
  int hh = lane & 7;
  int eslot = lane >> 3;
  float si = sird[r * 8 + hh].x;
  int beg = rptr[r], end = rptr[r + 1];
  float aexp = 0.f;
  int i = beg + eslot;
  for (; i + 8 < end; i += 16) {
    int c0 = csr_row_c[i], c1 = csr_row_c[i + 8];
    float sj0 = s_j[c0 * 8 + hh], sj1 = s_j[c1 * 8 + hh];
    float a0 = LRELU(si + sj0), a1 = LRELU(si + sj1);
    aexp += fexp2(a0) + fexp2(a1);
  }
  if (i < end) {
    int c = csr_row_c[i];
    float a = LRELU(si + s_j[c * 8 + hh]);
    aexp += fexp2(a);
  }
  aexp += __shfl_xor(aexp, 8);
  aexp += __shfl_xor(aexp, 16);
  aexp += __shfl_xor(aexp, 32);
  if (eslot == 0)
    reinterpret_cast<float*>(sird)[(r * 8 + hh) * 2 + 1] = 1.0f / (aexp + 1e-16f);
}

// ---------------------------------------------------------------------------
// Propagate 1 (nodes -> hyperedges): wave per hyperedge c, lane = channel.
// 16-edge software pipeline (16 payload loads in flight per wave).
__global__ __launch_bounds__(256) void prop1_csr(const int* __restrict__ cptr,
                                                 const unsigned short* __restrict__ csr_col_r,
                                                 const float* __restrict__ xh,
                                                 const float2* __restrict__ sird,
                                                 const float* __restrict__ s_j,
                                                 const float* __restrict__ Binv,
                                                 float* __restrict__ acc_e) {
  int wid = (blockIdx.x * 256 + threadIdx.x) >> 6;
  int lane = threadIdx.x & 63;
  if (wid >= NN) return;
  const int c = wid;
  const int hh = lane >> 3;
  const int j = lane & 7;
  const int abase = lane & 56;
  float sj = s_j[c * 8 + hh];
  int beg = cptr[c], end = cptr[c + 1];
  float acc = 0.f;
  int i = beg;
  for (; i + 16 <= end; i += 16) {
    int r0 = csr_col_r[i + j];
    int r1 = csr_col_r[i + 8 + j];
    float2 q0 = sird[r0 * 8 + hh];
    float2 q1 = sird[r1 * 8 + hh];
    float va[8], vb[8];
#pragma unroll
    for (int j2 = 0; j2 < 8; ++j2)
      va[j2] = xh[(__shfl(r0, j2) << 6) + lane];
#pragma unroll
    for (int j2 = 0; j2 < 8; ++j2)
      vb[j2] = xh[(__shfl(r1, j2) << 6) + lane];
    float a0 = fexp2(LRELU(q0.x + sj)) * q0.y;
    float a1 = fexp2(LRELU(q1.x + sj)) * q1.y;
#pragma unroll
    for (int j2 = 0; j2 < 8; ++j2)
      acc = fmaf(va[j2], __shfl(a0, abase + j2), acc);
#pragma unroll
    for (int j2 = 0; j2 < 8; ++j2)
      acc = fmaf(vb[j2], __shfl(a1, abase + j2), acc);
  }
  for (; i + 8 <= end; i += 8) {
    int rj = csr_col_r[i + j];
    float2 q = sird[rj * 8 + hh];
    float va[8];
#pragma unroll
    for (int j2 = 0; j2 < 8; ++j2)
      va[j2] = xh[(__shfl(rj, j2) << 6) + lane];
    float aexp = fexp2(LRELU(q.x + sj)) * q.y;
#pragma unroll
    for (int j2 = 0; j2 < 8; ++j2)
      acc = fmaf(va[j2], __shfl(aexp, abase + j2), acc);
  }
  for (; i < end; ++i) {
    int r = csr_col_r[i];
    float2 q = sird[r * 8 + hh];
    float a = LRELU(q.x + sj);
    acc = fmaf(xh[(r << 6) + lane], fexp2(a) * q.y, acc);
  }
  acc_e[(c << 6) + lane] = acc * Binv[c];
}

// ---------------------------------------------------------------------------
// Propagate 2 (hyperedges -> nodes) + finish1: wave per node r.
__global__ __launch_bounds__(256) void prop2_csr(const int* __restrict__ rptr,
                                                 const unsigned short* __restrict__ csr_row_c,
                                                 const float* __restrict__ acc_e,
                                                 const float2* __restrict__ sird,
                                                 const float* __restrict__ s_j,
                                                 const float* __restrict__ dinv,
                                                 const float* __restrict__ b1,
                                                 float* __restrict__ h) {
  int wid = (blockIdx.x * 256 + threadIdx.x) >> 6;
  int lane = threadIdx.x & 63;
  if (wid >= NN) return;
  const int r = wid;
  const int hh = lane >> 3;
  const int j = lane & 7;
  const int abase = lane & 56;
  float2 sr = sird[r * 8 + hh];
  const float si = sr.x, rd = sr.y;
  int beg = rptr[r], end = rptr[r + 1];
  float acc = 0.f;
  int i = beg;
  for (; i + 16 <= end; i += 16) {
    int c0 = csr_row_c[i + j];
    int c1 = csr_row_c[i + 8 + j];
    float sj0 = s_j[c0 * 8 + hh];
    float sj1 = s_j[c1 * 8 + hh];
    float va[8], vb[8];
#pragma unroll
    for (int j2 = 0; j2 < 8; ++j2)
      va[j2] = acc_e[(__shfl(c0, j2) << 6) + lane];
#pragma unroll
    for (int j2 = 0; j2 < 8; ++j2)
      vb[j2] = acc_e[(__shfl(c1, j2) << 6) + lane];
    float a0 = fexp2(LRELU(si + sj0));
    float a1 = fexp2(LRELU(si + sj1));
#pragma unroll
    for (int j2 = 0; j2 < 8; ++j2)
      acc = fmaf(va[j2], __shfl(a0, abase + j2), acc);
#pragma unroll
    for (int j2 = 0; j2 < 8; ++j2)
      acc = fmaf(vb[j2], __shfl(a1, abase + j2), acc);
  }
  for (; i + 8 <= end; i += 8) {
    int cj = csr_row_c[i + j];
    float sjv = s_j[cj * 8 + hh];
    float va[8];
#pragma unroll
    for (int j2 = 0; j2 < 8; ++j2)
      va[j2] = acc_e[(__shfl(cj, j2) << 6) + lane];
    float aexp = fexp2(LRELU(si + sjv));
#pragma unroll
    for (int j2 = 0; j2 < 8; ++j2)
      acc = fmaf(va[j2], __shfl(aexp, abase + j2), acc);
  }
  for (; i < end; ++i) {
    int cc = csr_row_c[i];
    float aexp = fexp2(LRELU(si + s_j[cc * 8 + hh]));
    acc = fmaf(acc_e[(cc << 6) + lane], aexp, acc);
  }
  acc *= rd;
  float v = fmaf(acc, dinv[r], b1[lane]);
  h[(r << 6) + lane] = v > 0.f ? v : expm1f(v);
}

// ---------------------------------------------------------------------------
// GEMM2: xh2[n,k] = sum_c h[n,c]*W2[c,k]  (k<7; slot 7 zeroed)
__global__ __launch_bounds__(256) void gemm2_kernel(const float* __restrict__ h,
                                                    const float* __restrict__ W2,
                                                    float* __restrict__ xh2) {
  int t = blockIdx.x * 256 + threadIdx.x;
  if (t >= NN * 8) return;
  int n = t >> 3, k = t & 7;
  if (k == 7) { xh2[t] = 0.f; return; }
  const float* hp = h + (size_t)n * HID;
  float acc = 0.f;
#pragma unroll
  for (int c = 0; c < HID; ++c) acc = fmaf(hp[c], W2[c * NCLS + k], acc);
  xh2[t] = acc;
}

// ---------------------------------------------------------------------------
// Layer-2 propagate 1: acc_e2[g] = Binv[g] * sum_r xh2[r]
__global__ __launch_bounds__(256) void prop3_csr(const int* __restrict__ cptr,
                                                 const unsigned short* __restrict__ csr_col_r,
                                                 const float* __restrict__ xh2,
                                                 const float* __restrict__ Binv,
                                                 float* __restrict__ acc_e2) {
  int t = blockIdx.x * 256 + threadIdx.x;
  int g = t >> 3, k = t & 7;
  if (g >= NN) return;
  int beg = cptr[g], end = cptr[g + 1];
  float acc = 0.f;
  int i = beg;
  for (; i + 3 < end; i += 4) {
    int r0 = csr_col_r[i], r1 = csr_col_r[i + 1];
    int r2 = csr_col_r[i + 2], r3 = csr_col_r[i + 3];
    float v0 = xh2[r0 * 8 + k], v1 = xh2[r1 * 8 + k];
    float v2 = xh2[r2 * 8 + k], v3 = xh2[r3 * 8 + k];
    acc += (v0 + v1) + (v2 + v3);
  }
  for (; i < end; ++i) acc += xh2[csr_col_r[i] * 8 + k];
  acc_e2[g * 8 + k] = acc * Binv[g];
}

// ---------------------------------------------------------------------------
// Layer-2 propagate 2 + log_softmax: 8 lanes per node.
__global__ __launch_bounds__(256) void prop4_csr(const int* __restrict__ rptr,
                                                 const unsigned short* __restrict__ csr_row_c,
                                                 const float* __restrict__ acc_e2,
                                                 const float* __restrict__ dinv,
                                                 const float* __restrict__ b2,
                                                 float* __restrict__ out) {
  int t = blockIdx.x * 256 + threadIdx.x;
  int r = t >> 3, k = t & 7;
  if (r >= NN) return;
  int beg = rptr[r], end = rptr[r + 1];
  float acc = 0.f;
  int i = beg;
  for (; i + 3 < end; i += 4) {
    int c0 = csr_row_c[i], c1 = csr_row_c[i + 1];
    int c2 = csr_row_c[i + 2], c3 = csr_row_c[i + 3];
    float v0 = acc_e2[c0 * 8 + k], v1 = acc_e2[c1 * 8 + k];
    float v2 = acc_e2[c2 * 8 + k], v3 = acc_e2[c3 * 8 + k];
    acc += (v0 + v1) + (v2 + v3);
  }
  for (; i < end; ++i) acc += acc_e2[csr_row_c[i] * 8 + k];
  float v = (k < NCLS) ? fmaf(acc, dinv[r], b2[k]) : -INFINITY;
  float m = v;
  m = fmaxf(m, __shfl_xor(m, 1, 8));
  m = fmaxf(m, __shfl_xor(m, 2, 8));
  m = fmaxf(m, __shfl_xor(m, 4, 8));
  float ex = (k < NCLS) ? expf(v - m) : 0.f;
  float s = ex;
  s += __shfl_xor(s, 1, 8);
  s += __shfl_xor(s, 2, 8);
  s += __shfl_xor(s, 4, 8);
  float lse = m + logf(s);
  if (k < NCLS) out[(size_t)r * NCLS + k] = v - lse;
}

// ---------------------------------------------------------------------------
extern "C" void kernel_launch(void* const* d_in, const int* in_sizes, int n_in,
                              void* d_out, int out_size, void* d_ws, size_t ws_size,
                              hipStream_t stream) {
  const float* x    = (const float*)d_in[0];
  const int*   ei   = (const int*)d_in[1];
  const float* hw   = (const float*)d_in[2];
  const float* W1   = (const float*)d_in[3];
  const float* att1 = (const float*)d_in[4];
  const float* b1   = (const float*)d_in[5];
  const float* W2   = (const float*)d_in[6];
  const float* b2   = (const float*)d_in[7];
  float* out = (float*)d_out;
  float* ws  = (float*)d_ws;

  float* xh     = ws + OFF_XH;     // gemm1 partial p0, then xh = p0+p1
  float* s_j    = ws + OFF_SJ;
  float2* sird  = (float2*)(ws + OFF_SIRD);
  float* dinv   = ws + OFF_DINV;
  float* Binv   = ws + OFF_BINV;
  float* acc_e  = ws + OFF_ACCE;
  float* hbuf   = ws + OFF_H;      // gemm1 partial p1, then h (prop2 output)
  float* xh2    = ws + OFF_XH2;
  float* acc_e2 = ws + OFF_ACCE2;
  int* rptr = (int*)(ws + OFF_RPTR);
  int* cptr = (int*)(ws + OFF_CPTR);
  int* bh_r = (int*)(ws + OFF_BHR);
  int* bh_c = (int*)(ws + OFF_BHC);
  int* bs_r = (int*)(ws + OFF_BSR);
  int* bs_c = (int*)(ws + OFF_BSC);
  int* bc_r = (int*)(ws + OFF_BCR);
  int* bc_c = (int*)(ws + OFF_BCC);
  unsigned short* csr_row_c = (unsigned short*)(ws + OFF_CSRRC);
  unsigned short* csr_col_r = (unsigned short*)(ws + OFF_CSRCR);
  int* tmp_r = (int*)(ws + OFF_XH);    // aliases xh (consumed before gemm1 writes)
  int* tmp_c = (int*)(ws + OFF_ACCE);  // aliases acc_e

  // --- CSR build (bucketed counting sort, both orderings) ---
  zero_small<<<1, 512, 0, stream>>>(bh_r, bh_c);
  bucket_hist<<<256, 256, 0, stream>>>(ei, bh_r, bh_c);
  bucket_scan<<<1, 512, 0, stream>>>(bh_r, bh_c, bs_r, bs_c, bc_r, bc_c);
  phaseA<<<(EE + EPB - 1) / EPB, 256, 0, stream>>>(ei, bc_r, bc_c, tmp_r, tmp_c);
  phaseB<<<2 * NB, 256, 0, stream>>>(tmp_r, tmp_c, bs_r, bs_c, hw,
                                     rptr, cptr, csr_row_c, csr_col_r, Binv, dinv);

  // --- Layer 1 ---
  {
    dim3 g((NN + 63) / 64, 2);
    gemm1_kernel<<<g, 256, 0, stream>>>(x, W1, xh, hbuf);
  }
  attscore_kernel<<<(NN * NHEAD + 255) / 256, 256, 0, stream>>>(xh, hbuf, att1, sird, s_j);
  den_csr<<<(NN * 64 + 255) / 256, 256, 0, stream>>>(rptr, csr_row_c, s_j, sird);
  prop1_csr<<<(NN * 64 + 255) / 256, 256, 0, stream>>>(cptr, csr_col_r, xh, sird, s_j, Binv, acc_e);
  prop2_csr<<<(NN * 64 + 255) / 256, 256, 0, stream>>>(rptr, csr_row_c, acc_e, sird, s_j,
                                                       dinv, b1, hbuf);

  // --- Layer 2 ---
  gemm2_kernel<<<(NN * 8 + 255) / 256, 256, 0, stream>>>(hbuf, W2, xh2);
  prop3_csr<<<(NN * 8 + 255) / 256, 256, 0, stream>>>(cptr, csr_col_r, xh2, Binv, acc_e2);
  prop4_csr<<<(NN * 8 + 255) / 256, 256, 0, stream>>>(rptr, csr_row_c, acc_e2, dinv, b2, out);
}

// Round 13
// 318.864 us; speedup vs baseline: 1.5746x; 1.0805x over previous
//
#include <hip/hip_runtime.h>
#include <hip/hip_bf16.h>
#include <cmath>

// Problem constants (match reference setup_inputs)
#define NN    50000
#define EE    1600000
#define FIN   512
#define NHEAD 8
#define OUT1  8
#define HID   64      // NHEAD*OUT1
#define NCLS  7

#define NB    391     // ceil(NN/128) buckets of 128 nodes
#define EPB   4096    // edges per block in phase A
#define LOG2E 1.4426950408889634f

// ---------------------------------------------------------------------------
// Workspace layout (4-byte elements):
//   p0      @ 0          N*64   (tmp_r aliases during CSR build; gemm1 p0)
//   s_j     @ 3,200,000  N*8    (pre-scaled by log2e)
//   sird    @ 3,600,000  N*8 float2  {s_i*log2e, 1/den}
//   dinv    @ 4,400,000  N
//   Binv    @ 4,450,000  N
//   xh16    @ 4,500,000  N*64 bf16 = 800K ints  (tmp_c aliases during build)
//   acc_e16 @ 5,300,000  N*64 bf16 = 800K ints
//   h       @ 7,700,000  N*64   (gemm1 partial p1 before prop2 writes h)
//   xh2     @ 10,900,000 N*8
//   acc_e2  @ 11,300,000 N*8
//   rptr    @ 11,700,000 N+1  int
//   cptr    @ 11,760,000 N+1  int
//   bh_r/bh_c/bs_r/bs_c/bc_r/bc_c @ 11,820,000 + k*1000
//   csr_row_c @ 11,830,000 E  ushort
//   csr_col_r @ 12,700,000 E  ushort
// ---------------------------------------------------------------------------
#define OFF_P0     0
#define OFF_SJ     3200000
#define OFF_SIRD   3600000
#define OFF_DINV   4400000
#define OFF_BINV   4450000
#define OFF_XH16   4500000
#define OFF_ACCE16 5300000
#define OFF_H      7700000
#define OFF_XH2    10900000
#define OFF_ACCE2  11300000
#define OFF_RPTR   11700000
#define OFF_CPTR   11760000
#define OFF_BHR    11820000
#define OFF_BHC    11821000
#define OFF_BSR    11822000
#define OFF_BSC    11823000
#define OFF_BCR    11824000
#define OFF_BCC    11825000
#define OFF_CSRRC  11830000
#define OFF_CSRCR  12700000

#define LRELU(a) ((a) > 0.f ? (a) : 0.2f * (a))

__device__ __forceinline__ float fexp2(float x) {
#if __has_builtin(__builtin_amdgcn_exp2f)
  return __builtin_amdgcn_exp2f(x);
#else
  return exp2f(x);
#endif
}

__device__ __forceinline__ float bf2f(unsigned short u) {
  union { unsigned int i; float f; } v;
  v.i = ((unsigned int)u) << 16;
  return v.f;
}
__device__ __forceinline__ unsigned short f2bf(float f) {
  union { float f; unsigned int i; } v;
  v.f = f;
  unsigned int r = v.i + 0x7FFFu + ((v.i >> 16) & 1u);  // RTN-even
  return (unsigned short)(r >> 16);
}

// ---------------------------------------------------------------------------
__global__ __launch_bounds__(512) void zero_small(int* __restrict__ bh_r,
                                                  int* __restrict__ bh_c) {
  int t = threadIdx.x;
  if (t <= NB) { bh_r[t] = 0; bh_c[t] = 0; }
}

// ---------------------------------------------------------------------------
__global__ __launch_bounds__(256) void bucket_hist(const int* __restrict__ ei,
                                                   int* __restrict__ bh_r,
                                                   int* __restrict__ bh_c) {
  __shared__ int hr[NB], hc[NB];
  int t = threadIdx.x;
  for (int i = t; i < NB; i += 256) { hr[i] = 0; hc[i] = 0; }
  __syncthreads();
  for (int i = blockIdx.x * 256 + t; i < EE; i += gridDim.x * 256) {
    atomicAdd(hr + (ei[i] >> 7), 1);
    atomicAdd(hc + (ei[EE + i] >> 7), 1);
  }
  __syncthreads();
  for (int i = t; i < NB; i += 256) {
    if (hr[i]) atomicAdd(bh_r + i, hr[i]);
    if (hc[i]) atomicAdd(bh_c + i, hc[i]);
  }
}

// ---------------------------------------------------------------------------
__global__ __launch_bounds__(512) void bucket_scan(const int* __restrict__ bh_r,
                                                   const int* __restrict__ bh_c,
                                                   int* __restrict__ bs_r,
                                                   int* __restrict__ bs_c,
                                                   int* __restrict__ bc_r,
                                                   int* __restrict__ bc_c) {
  __shared__ int lds[512];
  int t = threadIdx.x;
  for (int side = 0; side < 2; ++side) {
    const int* bh = side ? bh_c : bh_r;
    int* bs = side ? bs_c : bs_r;
    int* bc = side ? bc_c : bc_r;
    int v = (t < NB) ? bh[t] : 0;
    lds[t] = v;
    __syncthreads();
    for (int off = 1; off < 512; off <<= 1) {
      int u = (t >= off) ? lds[t - off] : 0;
      __syncthreads();
      lds[t] += u;
      __syncthreads();
    }
    int excl = lds[t] - v;
    if (t <= NB) bs[t] = excl;
    if (t < NB) bc[t] = excl;
    __syncthreads();
  }
}

// ---------------------------------------------------------------------------
__global__ __launch_bounds__(256) void phaseA(const int* __restrict__ ei,
                                              int* __restrict__ bc_r,
                                              int* __restrict__ bc_c,
                                              int* __restrict__ tmp_r,
                                              int* __restrict__ tmp_c) {
  __shared__ int er[EPB];
  __shared__ int ec[EPB];
  __shared__ int hr[NB], hc[NB];
  const int e0 = blockIdx.x * EPB;
  const int cntE = min(EPB, EE - e0);
  const int t = threadIdx.x;
  for (int i = t; i < cntE; i += 256) { er[i] = ei[e0 + i]; ec[i] = ei[EE + e0 + i]; }
  for (int i = t; i < NB; i += 256) { hr[i] = 0; hc[i] = 0; }
  __syncthreads();
  for (int i = t; i < cntE; i += 256) {
    atomicAdd(hr + (er[i] >> 7), 1);
    atomicAdd(hc + (ec[i] >> 7), 1);
  }
  __syncthreads();
  for (int i = t; i < NB; i += 256) {
    int n = hr[i];
    hr[i] = n ? atomicAdd(bc_r + i, n) : 0;
    n = hc[i];
    hc[i] = n ? atomicAdd(bc_c + i, n) : 0;
  }
  __syncthreads();
  for (int i = t; i < cntE; i += 256) {
    int r = er[i], c = ec[i];
    int pr = atomicAdd(hr + (r >> 7), 1);
    tmp_r[pr] = ((r & 127) << 16) | c;
    int pc = atomicAdd(hc + (c >> 7), 1);
    tmp_c[pc] = ((c & 127) << 16) | r;
  }
}

// ---------------------------------------------------------------------------
// Phase B: one block per (side, bucket).  Emits 16-bit CSR entries.
// Row side additionally accumulates D = sum hw[col] and writes dinv.
__global__ __launch_bounds__(256) void phaseB(const int* __restrict__ tmp_r,
                                              const int* __restrict__ tmp_c,
                                              const int* __restrict__ bs_r,
                                              const int* __restrict__ bs_c,
                                              const float* __restrict__ hw,
                                              int* __restrict__ rptr,
                                              int* __restrict__ cptr,
                                              unsigned short* __restrict__ csr_row_c,
                                              unsigned short* __restrict__ csr_col_r,
                                              float* __restrict__ Binv,
                                              float* __restrict__ dinv) {
  const int side = blockIdx.x >= NB ? 1 : 0;
  const int b = blockIdx.x - side * NB;
  const int* tmp = side ? tmp_c : tmp_r;
  const int* bs = side ? bs_c : bs_r;
  int* ptr = side ? cptr : rptr;
  unsigned short* csr = side ? csr_col_r : csr_row_c;

  const int base = bs[b];
  const int M = bs[b + 1] - base;
  __shared__ int cnt[128], pre[128], cur[128];
  __shared__ float ds[128];
  const int t = threadIdx.x;
  if (t < 128) { cnt[t] = 0; ds[t] = 0.f; }
  __syncthreads();
  for (int i = t; i < M; i += 256) atomicAdd(cnt + (tmp[base + i] >> 16), 1);
  __syncthreads();
  if (t < 128) pre[t] = cnt[t];
  __syncthreads();
  for (int off = 1; off < 128; off <<= 1) {
    int u = (t >= off && t < 128) ? pre[t - off] : 0;
    __syncthreads();
    if (t < 128) pre[t] += u;
    __syncthreads();
  }
  const int node0 = b << 7;
  if (t < 128) {
    int excl = pre[t] - cnt[t];
    int g = node0 + t;
    if (g <= NN) ptr[g] = base + excl;
    cur[t] = base + excl;
    if (side && g < NN) Binv[g] = cnt[t] > 0 ? hw[g] / (float)cnt[t] : 0.f;
  }
  __syncthreads();
  for (int i = t; i < M; i += 256) {
    int e = tmp[base + i];
    int own = e >> 16;
    int other = e & 0xFFFF;
    int pos = atomicAdd(cur + own, 1);
    csr[pos] = (unsigned short)other;
    if (!side) atomicAdd(ds + own, hw[other]);
  }
  __syncthreads();
  if (!side && t < 128) {
    int g = node0 + t;
    if (g < NN) dinv[g] = ds[t] > 0.f ? 1.0f / ds[t] : 0.f;
  }
}

// ---------------------------------------------------------------------------
// GEMM1 split-K: blockIdx.y selects K-half and the output partial buffer.
__global__ __launch_bounds__(256) void gemm1_kernel(const float* __restrict__ x,
                                                    const float* __restrict__ W1,
                                                    float* __restrict__ p0,
                                                    float* __restrict__ p1) {
  __shared__ float lx[32][66];
  __shared__ float lw[32][68];
  const int t = threadIdx.x;
  const int row0 = blockIdx.x * 64;
  const int kbase = blockIdx.y * (FIN / 2);
  float* __restrict__ dst = blockIdx.y ? p1 : p0;
  const int ty = t >> 4, tx = t & 15;
  const int r0 = ty * 4, c0 = tx * 4;
  const int sr = t >> 2;
  const int sk = (t & 3) * 8;
  const int grow = row0 + sr;
  const int wk = t >> 3;
  const int wc = (t & 7) * 8;

  float acc[4][4] = {};

  for (int kb = kbase; kb < kbase + FIN / 2; kb += 32) {
    {
      float4 a0 = make_float4(0.f, 0.f, 0.f, 0.f), a1 = a0;
      if (grow < NN) {
        const float4* p = reinterpret_cast<const float4*>(x + (size_t)grow * FIN + kb + sk);
        a0 = p[0]; a1 = p[1];
      }
      lx[sk + 0][sr] = a0.x; lx[sk + 1][sr] = a0.y;
      lx[sk + 2][sr] = a0.z; lx[sk + 3][sr] = a0.w;
      lx[sk + 4][sr] = a1.x; lx[sk + 5][sr] = a1.y;
      lx[sk + 6][sr] = a1.z; lx[sk + 7][sr] = a1.w;
    }
    {
      const float4* q = reinterpret_cast<const float4*>(W1 + (size_t)(kb + wk) * HID + wc);
      float4 b0 = q[0], b1v = q[1];
      *reinterpret_cast<float4*>(&lw[wk][wc]) = b0;
      *reinterpret_cast<float4*>(&lw[wk][wc + 4]) = b1v;
    }
    __syncthreads();
#pragma unroll
    for (int kk = 0; kk < 32; ++kk) {
      const float4 af = *reinterpret_cast<const float4*>(&lx[kk][r0]);
      const float4 bf = *reinterpret_cast<const float4*>(&lw[kk][c0]);
      const float a4[4] = {af.x, af.y, af.z, af.w};
      const float b4[4] = {bf.x, bf.y, bf.z, bf.w};
#pragma unroll
      for (int i = 0; i < 4; ++i)
#pragma unroll
        for (int j = 0; j < 4; ++j)
          acc[i][j] = fmaf(a4[i], b4[j], acc[i][j]);
    }
    __syncthreads();
  }
#pragma unroll
  for (int i = 0; i < 4; ++i) {
    int gr = row0 + r0 + i;
    if (gr < NN) {
      float4 v = make_float4(acc[i][0], acc[i][1], acc[i][2], acc[i][3]);
      *reinterpret_cast<float4*>(dst + (size_t)gr * HID + c0) = v;
    }
  }
}

// ---------------------------------------------------------------------------
// Attention projections + split-K reduction.  Scores computed from the f32
// sum; xh stored ONLY as bf16 (halves prop1's gather payload).
__global__ __launch_bounds__(256) void attscore_kernel(const float* __restrict__ p0,
                                                       const float* __restrict__ p1,
                                                       const float* __restrict__ att1,
                                                       unsigned short* __restrict__ xh16,
                                                       float2* __restrict__ sird,
                                                       float* __restrict__ s_j) {
  int t = blockIdx.x * 256 + threadIdx.x;
  if (t >= NN * NHEAD) return;
  int hh = t & 7;
  const size_t base = (size_t)t * 8;
  float4 a0 = *reinterpret_cast<const float4*>(p0 + base);
  float4 a1 = *reinterpret_cast<const float4*>(p0 + base + 4);
  float4 q0 = *reinterpret_cast<const float4*>(p1 + base);
  float4 q1 = *reinterpret_cast<const float4*>(p1 + base + 4);
  float v[8] = {a0.x + q0.x, a0.y + q0.y, a0.z + q0.z, a0.w + q0.w,
                a1.x + q1.x, a1.y + q1.y, a1.z + q1.z, a1.w + q1.w};
  float si = 0.f, sj = 0.f;
#pragma unroll
  for (int c = 0; c < OUT1; ++c) {
    si = fmaf(v[c], att1[hh * 16 + c], si);
    sj = fmaf(v[c], att1[hh * 16 + 8 + c], sj);
  }
  uint4 packed;
  packed.x = (unsigned int)f2bf(v[0]) | ((unsigned int)f2bf(v[1]) << 16);
  packed.y = (unsigned int)f2bf(v[2]) | ((unsigned int)f2bf(v[3]) << 16);
  packed.z = (unsigned int)f2bf(v[4]) | ((unsigned int)f2bf(v[5]) << 16);
  packed.w = (unsigned int)f2bf(v[6]) | ((unsigned int)f2bf(v[7]) << 16);
  *reinterpret_cast<uint4*>(xh16 + base) = packed;
  sird[t] = make_float2(si * LOG2E, 0.f);
  s_j[t] = sj * LOG2E;
}

// ---------------------------------------------------------------------------
// Softmax denominator (reciprocal -> sird.y).
__global__ __launch_bounds__(256) void den_csr(const int* __restrict__ rptr,
                                               const unsigned short* __restrict__ csr_row_c,
                                               const float* __restrict__ s_j,
                                               float2* __restrict__ sird) {
  int wid = (blockIdx.x * 256 + threadIdx.x) >> 6;
  int lane = threadIdx.x & 63;
  if (wid >= NN) return;
  int r = wid;
  int hh = lane & 7;
  int eslot = lane >> 3;
  float si = sird[r * 8 + hh].x;
  int beg = rptr[r], end = rptr[r + 1];
  float aexp = 0.f;
  int i = beg + eslot;
  for (; i + 8 < end; i += 16) {
    int c0 = csr_row_c[i], c1 = csr_row_c[i + 8];
    float sj0 = s_j[c0 * 8 + hh], sj1 = s_j[c1 * 8 + hh];
    float a0 = LRELU(si + sj0), a1 = LRELU(si + sj1);
    aexp += fexp2(a0) + fexp2(a1);
  }
  if (i < end) {
    int c = csr_row_c[i];
    float a = LRELU(si + s_j[c * 8 + hh]);
    aexp += fexp2(a);
  }
  aexp += __shfl_xor(aexp, 8);
  aexp += __shfl_xor(aexp, 16);
  aexp += __shfl_xor(aexp, 32);
  if (eslot == 0)
    reinterpret_cast<float*>(sird)[(r * 8 + hh) * 2 + 1] = 1.0f / (aexp + 1e-16f);
}

// ---------------------------------------------------------------------------
// Propagate 1 (nodes -> hyperedges): wave per hyperedge c, lane = channel.
// bf16 payload gathers (128B/row), f32 accumulation, bf16 output.
__global__ __launch_bounds__(256) void prop1_csr(const int* __restrict__ cptr,
                                                 const unsigned short* __restrict__ csr_col_r,
                                                 const unsigned short* __restrict__ xh16,
                                                 const float2* __restrict__ sird,
                                                 const float* __restrict__ s_j,
                                                 const float* __restrict__ Binv,
                                                 unsigned short* __restrict__ acc_e16) {
  int wid = (blockIdx.x * 256 + threadIdx.x) >> 6;
  int lane = threadIdx.x & 63;
  if (wid >= NN) return;
  const int c = wid;
  const int hh = lane >> 3;
  const int j = lane & 7;
  const int abase = lane & 56;
  float sj = s_j[c * 8 + hh];
  int beg = cptr[c], end = cptr[c + 1];
  float acc = 0.f;
  int i = beg;
  for (; i + 16 <= end; i += 16) {
    int r0 = csr_col_r[i + j];
    int r1 = csr_col_r[i + 8 + j];
    float2 q0 = sird[r0 * 8 + hh];
    float2 q1 = sird[r1 * 8 + hh];
    unsigned short va[8], vb[8];
#pragma unroll
    for (int j2 = 0; j2 < 8; ++j2)
      va[j2] = xh16[(__shfl(r0, j2) << 6) + lane];
#pragma unroll
    for (int j2 = 0; j2 < 8; ++j2)
      vb[j2] = xh16[(__shfl(r1, j2) << 6) + lane];
    float a0 = fexp2(LRELU(q0.x + sj)) * q0.y;
    float a1 = fexp2(LRELU(q1.x + sj)) * q1.y;
#pragma unroll
    for (int j2 = 0; j2 < 8; ++j2)
      acc = fmaf(bf2f(va[j2]), __shfl(a0, abase + j2), acc);
#pragma unroll
    for (int j2 = 0; j2 < 8; ++j2)
      acc = fmaf(bf2f(vb[j2]), __shfl(a1, abase + j2), acc);
  }
  for (; i + 8 <= end; i += 8) {
    int rj = csr_col_r[i + j];
    float2 q = sird[rj * 8 + hh];
    unsigned short va[8];
#pragma unroll
    for (int j2 = 0; j2 < 8; ++j2)
      va[j2] = xh16[(__shfl(rj, j2) << 6) + lane];
    float aexp = fexp2(LRELU(q.x + sj)) * q.y;
#pragma unroll
    for (int j2 = 0; j2 < 8; ++j2)
      acc = fmaf(bf2f(va[j2]), __shfl(aexp, abase + j2), acc);
  }
  for (; i < end; ++i) {
    int r = csr_col_r[i];
    float2 q = sird[r * 8 + hh];
    float a = LRELU(q.x + sj);
    acc = fmaf(bf2f(xh16[(r << 6) + lane]), fexp2(a) * q.y, acc);
  }
  acc_e16[(c << 6) + lane] = f2bf(acc * Binv[c]);
}

// ---------------------------------------------------------------------------
// Propagate 2 (hyperedges -> nodes) + finish1: wave per node r.
// bf16 payload gathers, f32 everything else.
__global__ __launch_bounds__(256) void prop2_csr(const int* __restrict__ rptr,
                                                 const unsigned short* __restrict__ csr_row_c,
                                                 const unsigned short* __restrict__ acc_e16,
                                                 const float2* __restrict__ sird,
                                                 const float* __restrict__ s_j,
                                                 const float* __restrict__ dinv,
                                                 const float* __restrict__ b1,
                                                 float* __restrict__ h) {
  int wid = (blockIdx.x * 256 + threadIdx.x) >> 6;
  int lane = threadIdx.x & 63;
  if (wid >= NN) return;
  const int r = wid;
  const int hh = lane >> 3;
  const int j = lane & 7;
  const int abase = lane & 56;
  float2 sr = sird[r * 8 + hh];
  const float si = sr.x, rd = sr.y;
  int beg = rptr[r], end = rptr[r + 1];
  float acc = 0.f;
  int i = beg;
  for (; i + 16 <= end; i += 16) {
    int c0 = csr_row_c[i + j];
    int c1 = csr_row_c[i + 8 + j];
    float sj0 = s_j[c0 * 8 + hh];
    float sj1 = s_j[c1 * 8 + hh];
    unsigned short va[8], vb[8];
#pragma unroll
    for (int j2 = 0; j2 < 8; ++j2)
      va[j2] = acc_e16[(__shfl(c0, j2) << 6) + lane];
#pragma unroll
    for (int j2 = 0; j2 < 8; ++j2)
      vb[j2] = acc_e16[(__shfl(c1, j2) << 6) + lane];
    float a0 = fexp2(LRELU(si + sj0));
    float a1 = fexp2(LRELU(si + sj1));
#pragma unroll
    for (int j2 = 0; j2 < 8; ++j2)
      acc = fmaf(bf2f(va[j2]), __shfl(a0, abase + j2), acc);
#pragma unroll
    for (int j2 = 0; j2 < 8; ++j2)
      acc = fmaf(bf2f(vb[j2]), __shfl(a1, abase + j2), acc);
  }
  for (; i + 8 <= end; i += 8) {
    int cj = csr_row_c[i + j];
    float sjv = s_j[cj * 8 + hh];
    unsigned short va[8];
#pragma unroll
    for (int j2 = 0; j2 < 8; ++j2)
      va[j2] = acc_e16[(__shfl(cj, j2) << 6) + lane];
    float aexp = fexp2(LRELU(si + sjv));
#pragma unroll
    for (int j2 = 0; j2 < 8; ++j2)
      acc = fmaf(bf2f(va[j2]), __shfl(aexp, abase + j2), acc);
  }
  for (; i < end; ++i) {
    int cc = csr_row_c[i];
    float aexp = fexp2(LRELU(si + s_j[cc * 8 + hh]));
    acc = fmaf(bf2f(acc_e16[(cc << 6) + lane]), aexp, acc);
  }
  acc *= rd;
  float v = fmaf(acc, dinv[r], b1[lane]);
  h[(r << 6) + lane] = v > 0.f ? v : expm1f(v);
}

// ---------------------------------------------------------------------------
// GEMM2: xh2[n,k] = sum_c h[n,c]*W2[c,k]  (k<7; slot 7 zeroed)
__global__ __launch_bounds__(256) void gemm2_kernel(const float* __restrict__ h,
                                                    const float* __restrict__ W2,
                                                    float* __restrict__ xh2) {
  int t = blockIdx.x * 256 + threadIdx.x;
  if (t >= NN * 8) return;
  int n = t >> 3, k = t & 7;
  if (k == 7) { xh2[t] = 0.f; return; }
  const float* hp = h + (size_t)n * HID;
  float acc = 0.f;
#pragma unroll
  for (int c = 0; c < HID; ++c) acc = fmaf(hp[c], W2[c * NCLS + k], acc);
  xh2[t] = acc;
}

// ---------------------------------------------------------------------------
// Layer-2 propagate 1: acc_e2[g] = Binv[g] * sum_r xh2[r]
__global__ __launch_bounds__(256) void prop3_csr(const int* __restrict__ cptr,
                                                 const unsigned short* __restrict__ csr_col_r,
                                                 const float* __restrict__ xh2,
                                                 const float* __restrict__ Binv,
                                                 float* __restrict__ acc_e2) {
  int t = blockIdx.x * 256 + threadIdx.x;
  int g = t >> 3, k = t & 7;
  if (g >= NN) return;
  int beg = cptr[g], end = cptr[g + 1];
  float acc = 0.f;
  int i = beg;
  for (; i + 3 < end; i += 4) {
    int r0 = csr_col_r[i], r1 = csr_col_r[i + 1];
    int r2 = csr_col_r[i + 2], r3 = csr_col_r[i + 3];
    float v0 = xh2[r0 * 8 + k], v1 = xh2[r1 * 8 + k];
    float v2 = xh2[r2 * 8 + k], v3 = xh2[r3 * 8 + k];
    acc += (v0 + v1) + (v2 + v3);
  }
  for (; i < end; ++i) acc += xh2[csr_col_r[i] * 8 + k];
  acc_e2[g * 8 + k] = acc * Binv[g];
}

// ---------------------------------------------------------------------------
// Layer-2 propagate 2 + log_softmax: 8 lanes per node.
__global__ __launch_bounds__(256) void prop4_csr(const int* __restrict__ rptr,
                                                 const unsigned short* __restrict__ csr_row_c,
                                                 const float* __restrict__ acc_e2,
                                                 const float* __restrict__ dinv,
                                                 const float* __restrict__ b2,
                                                 float* __restrict__ out) {
  int t = blockIdx.x * 256 + threadIdx.x;
  int r = t >> 3, k = t & 7;
  if (r >= NN) return;
  int beg = rptr[r], end = rptr[r + 1];
  float acc = 0.f;
  int i = beg;
  for (; i + 3 < end; i += 4) {
    int c0 = csr_row_c[i], c1 = csr_row_c[i + 1];
    int c2 = csr_row_c[i + 2], c3 = csr_row_c[i + 3];
    float v0 = acc_e2[c0 * 8 + k], v1 = acc_e2[c1 * 8 + k];
    float v2 = acc_e2[c2 * 8 + k], v3 = acc_e2[c3 * 8 + k];
    acc += (v0 + v1) + (v2 + v3);
  }
  for (; i < end; ++i) acc += acc_e2[csr_row_c[i] * 8 + k];
  float v = (k < NCLS) ? fmaf(acc, dinv[r], b2[k]) : -INFINITY;
  float m = v;
  m = fmaxf(m, __shfl_xor(m, 1, 8));
  m = fmaxf(m, __shfl_xor(m, 2, 8));
  m = fmaxf(m, __shfl_xor(m, 4, 8));
  float ex = (k < NCLS) ? expf(v - m) : 0.f;
  float s = ex;
  s += __shfl_xor(s, 1, 8);
  s += __shfl_xor(s, 2, 8);
  s += __shfl_xor(s, 4, 8);
  float lse = m + logf(s);
  if (k < NCLS) out[(size_t)r * NCLS + k] = v - lse;
}

// ---------------------------------------------------------------------------
extern "C" void kernel_launch(void* const* d_in, const int* in_sizes, int n_in,
                              void* d_out, int out_size, void* d_ws, size_t ws_size,
                              hipStream_t stream) {
  const float* x    = (const float*)d_in[0];
  const int*   ei   = (const int*)d_in[1];
  const float* hw   = (const float*)d_in[2];
  const float* W1   = (const float*)d_in[3];
  const float* att1 = (const float*)d_in[4];
  const float* b1   = (const float*)d_in[5];
  const float* W2   = (const float*)d_in[6];
  const float* b2   = (const float*)d_in[7];
  float* out = (float*)d_out;
  float* ws  = (float*)d_ws;

  float* p0buf  = ws + OFF_P0;     // gemm1 partial p0
  float* s_j    = ws + OFF_SJ;
  float2* sird  = (float2*)(ws + OFF_SIRD);
  float* dinv   = ws + OFF_DINV;
  float* Binv   = ws + OFF_BINV;
  unsigned short* xh16    = (unsigned short*)(ws + OFF_XH16);
  unsigned short* acc_e16 = (unsigned short*)(ws + OFF_ACCE16);
  float* hbuf   = ws + OFF_H;      // gemm1 partial p1, then h (prop2 output)
  float* xh2    = ws + OFF_XH2;
  float* acc_e2 = ws + OFF_ACCE2;
  int* rptr = (int*)(ws + OFF_RPTR);
  int* cptr = (int*)(ws + OFF_CPTR);
  int* bh_r = (int*)(ws + OFF_BHR);
  int* bh_c = (int*)(ws + OFF_BHC);
  int* bs_r = (int*)(ws + OFF_BSR);
  int* bs_c = (int*)(ws + OFF_BSC);
  int* bc_r = (int*)(ws + OFF_BCR);
  int* bc_c = (int*)(ws + OFF_BCC);
  unsigned short* csr_row_c = (unsigned short*)(ws + OFF_CSRRC);
  unsigned short* csr_col_r = (unsigned short*)(ws + OFF_CSRCR);
  int* tmp_r = (int*)(ws + OFF_P0);    // aliases p0 (consumed before gemm1)
  int* tmp_c = (int*)(ws + OFF_XH16);  // aliases xh16 region (consumed pre-attscore)

  // --- CSR build (bucketed counting sort, both orderings) ---
  zero_small<<<1, 512, 0, stream>>>(bh_r, bh_c);
  bucket_hist<<<256, 256, 0, stream>>>(ei, bh_r, bh_c);
  bucket_scan<<<1, 512, 0, stream>>>(bh_r, bh_c, bs_r, bs_c, bc_r, bc_c);
  phaseA<<<(EE + EPB - 1) / EPB, 256, 0, stream>>>(ei, bc_r, bc_c, tmp_r, tmp_c);
  phaseB<<<2 * NB, 256, 0, stream>>>(tmp_r, tmp_c, bs_r, bs_c, hw,
                                     rptr, cptr, csr_row_c, csr_col_r, Binv, dinv);

  // --- Layer 1 ---
  {
    dim3 g((NN + 63) / 64, 2);
    gemm1_kernel<<<g, 256, 0, stream>>>(x, W1, p0buf, hbuf);
  }
  attscore_kernel<<<(NN * NHEAD + 255) / 256, 256, 0, stream>>>(p0buf, hbuf, att1,
                                                                xh16, sird, s_j);
  den_csr<<<(NN * 64 + 255) / 256, 256, 0, stream>>>(rptr, csr_row_c, s_j, sird);
  prop1_csr<<<(NN * 64 + 255) / 256, 256, 0, stream>>>(cptr, csr_col_r, xh16, sird,
                                                       s_j, Binv, acc_e16);
  prop2_csr<<<(NN * 64 + 255) / 256, 256, 0, stream>>>(rptr, csr_row_c, acc_e16, sird,
                                                       s_j, dinv, b1, hbuf);

  // --- Layer 2 ---
  gemm2_kernel<<<(NN * 8 + 255) / 256, 256, 0, stream>>>(hbuf, W2, xh2);
  prop3_csr<<<(NN * 8 + 255) / 256, 256, 0, stream>>>(cptr, csr_col_r, xh2, Binv, acc_e2);
  prop4_csr<<<(NN * 8 + 255) / 256, 256, 0, stream>>>(rptr, csr_row_c, acc_e2, dinv, b2, out);
}

// Round 14
// 284.949 us; speedup vs baseline: 1.7620x; 1.1190x over previous
//
#include <hip/hip_runtime.h>
#include <hip/hip_bf16.h>
#include <cmath>

// Problem constants (match reference setup_inputs)
#define NN    50000
#define EE    1600000
#define FIN   512
#define NHEAD 8
#define OUT1  8
#define HID   64      // NHEAD*OUT1
#define NCLS  7

#define NB    391     // ceil(NN/128) buckets of 128 nodes
#define EPB   4096    // edges per block in phase A
#define LOG2E 1.4426950408889634f

// ---------------------------------------------------------------------------
// Workspace layout (4-byte elements):
//   (free)  @ 0          N*64   (tmp_r aliases during CSR build)
//   s_j     @ 3,200,000  N*8    (pre-scaled by log2e)
//   sird    @ 3,600,000  N*8 float2  {s_i*log2e, 1/den}
//   dinv    @ 4,400,000  N
//   Binv    @ 4,450,000  N
//   xh16    @ 4,500,000  N*64 bf16 = 800K ints  (tmp_c aliases during build)
//   acc_e16 @ 5,300,000  N*64 bf16 = 800K ints
//   h       @ 7,700,000  N*64   (W1T16 bf16 lives here before prop2 writes h)
//   xh2     @ 10,900,000 N*8
//   acc_e2  @ 11,300,000 N*8
//   rptr    @ 11,700,000 N+1  int
//   cptr    @ 11,760,000 N+1  int
//   bh_r/bh_c/bs_r/bs_c/bc_r/bc_c @ 11,820,000 + k*1000
//   csr_row_c @ 11,830,000 E  ushort
//   csr_col_r @ 12,700,000 E  ushort
// ---------------------------------------------------------------------------
#define OFF_P0     0
#define OFF_SJ     3200000
#define OFF_SIRD   3600000
#define OFF_DINV   4400000
#define OFF_BINV   4450000
#define OFF_XH16   4500000
#define OFF_ACCE16 5300000
#define OFF_H      7700000
#define OFF_XH2    10900000
#define OFF_ACCE2  11300000
#define OFF_RPTR   11700000
#define OFF_CPTR   11760000
#define OFF_BHR    11820000
#define OFF_BHC    11821000
#define OFF_BSR    11822000
#define OFF_BSC    11823000
#define OFF_BCR    11824000
#define OFF_BCC    11825000
#define OFF_CSRRC  11830000
#define OFF_CSRCR  12700000

#define LRELU(a) ((a) > 0.f ? (a) : 0.2f * (a))

typedef __attribute__((ext_vector_type(8))) short bf16x8;
typedef __attribute__((ext_vector_type(4))) float f32x4;

__device__ __forceinline__ float fexp2(float x) {
#if __has_builtin(__builtin_amdgcn_exp2f)
  return __builtin_amdgcn_exp2f(x);
#else
  return exp2f(x);
#endif
}

__device__ __forceinline__ float bf2f(unsigned short u) {
  union { unsigned int i; float f; } v;
  v.i = ((unsigned int)u) << 16;
  return v.f;
}
__device__ __forceinline__ unsigned short f2bf(float f) {
  union { float f; unsigned int i; } v;
  v.f = f;
  unsigned int r = v.i + 0x7FFFu + ((v.i >> 16) & 1u);  // RTN-even
  return (unsigned short)(r >> 16);
}

// ---------------------------------------------------------------------------
__global__ __launch_bounds__(512) void zero_small(int* __restrict__ bh_r,
                                                  int* __restrict__ bh_c) {
  int t = threadIdx.x;
  if (t <= NB) { bh_r[t] = 0; bh_c[t] = 0; }
}

// ---------------------------------------------------------------------------
// W1 [512][64] f32 -> W1T16 [64][512] bf16 (transposed, for MFMA B staging).
__global__ __launch_bounds__(256) void wconv_kernel(const float* __restrict__ W1,
                                                    unsigned short* __restrict__ w1t) {
  int idx = blockIdx.x * 256 + threadIdx.x;
  if (idx >= FIN * HID) return;
  int k = idx >> 6, col = idx & 63;
  w1t[col * FIN + k] = f2bf(W1[idx]);
}

// ---------------------------------------------------------------------------
__global__ __launch_bounds__(256) void bucket_hist(const int* __restrict__ ei,
                                                   int* __restrict__ bh_r,
                                                   int* __restrict__ bh_c) {
  __shared__ int hr[NB], hc[NB];
  int t = threadIdx.x;
  for (int i = t; i < NB; i += 256) { hr[i] = 0; hc[i] = 0; }
  __syncthreads();
  for (int i = blockIdx.x * 256 + t; i < EE; i += gridDim.x * 256) {
    atomicAdd(hr + (ei[i] >> 7), 1);
    atomicAdd(hc + (ei[EE + i] >> 7), 1);
  }
  __syncthreads();
  for (int i = t; i < NB; i += 256) {
    if (hr[i]) atomicAdd(bh_r + i, hr[i]);
    if (hc[i]) atomicAdd(bh_c + i, hc[i]);
  }
}

// ---------------------------------------------------------------------------
__global__ __launch_bounds__(512) void bucket_scan(const int* __restrict__ bh_r,
                                                   const int* __restrict__ bh_c,
                                                   int* __restrict__ bs_r,
                                                   int* __restrict__ bs_c,
                                                   int* __restrict__ bc_r,
                                                   int* __restrict__ bc_c) {
  __shared__ int lds[512];
  int t = threadIdx.x;
  for (int side = 0; side < 2; ++side) {
    const int* bh = side ? bh_c : bh_r;
    int* bs = side ? bs_c : bs_r;
    int* bc = side ? bc_c : bc_r;
    int v = (t < NB) ? bh[t] : 0;
    lds[t] = v;
    __syncthreads();
    for (int off = 1; off < 512; off <<= 1) {
      int u = (t >= off) ? lds[t - off] : 0;
      __syncthreads();
      lds[t] += u;
      __syncthreads();
    }
    int excl = lds[t] - v;
    if (t <= NB) bs[t] = excl;
    if (t < NB) bc[t] = excl;
    __syncthreads();
  }
}

// ---------------------------------------------------------------------------
__global__ __launch_bounds__(256) void phaseA(const int* __restrict__ ei,
                                              int* __restrict__ bc_r,
                                              int* __restrict__ bc_c,
                                              int* __restrict__ tmp_r,
                                              int* __restrict__ tmp_c) {
  __shared__ int er[EPB];
  __shared__ int ec[EPB];
  __shared__ int hr[NB], hc[NB];
  const int e0 = blockIdx.x * EPB;
  const int cntE = min(EPB, EE - e0);
  const int t = threadIdx.x;
  for (int i = t; i < cntE; i += 256) { er[i] = ei[e0 + i]; ec[i] = ei[EE + e0 + i]; }
  for (int i = t; i < NB; i += 256) { hr[i] = 0; hc[i] = 0; }
  __syncthreads();
  for (int i = t; i < cntE; i += 256) {
    atomicAdd(hr + (er[i] >> 7), 1);
    atomicAdd(hc + (ec[i] >> 7), 1);
  }
  __syncthreads();
  for (int i = t; i < NB; i += 256) {
    int n = hr[i];
    hr[i] = n ? atomicAdd(bc_r + i, n) : 0;
    n = hc[i];
    hc[i] = n ? atomicAdd(bc_c + i, n) : 0;
  }
  __syncthreads();
  for (int i = t; i < cntE; i += 256) {
    int r = er[i], c = ec[i];
    int pr = atomicAdd(hr + (r >> 7), 1);
    tmp_r[pr] = ((r & 127) << 16) | c;
    int pc = atomicAdd(hc + (c >> 7), 1);
    tmp_c[pc] = ((c & 127) << 16) | r;
  }
}

// ---------------------------------------------------------------------------
// Phase B: one block per (side, bucket).  Emits 16-bit CSR entries.
// Row side additionally accumulates D = sum hw[col] and writes dinv.
__global__ __launch_bounds__(256) void phaseB(const int* __restrict__ tmp_r,
                                              const int* __restrict__ tmp_c,
                                              const int* __restrict__ bs_r,
                                              const int* __restrict__ bs_c,
                                              const float* __restrict__ hw,
                                              int* __restrict__ rptr,
                                              int* __restrict__ cptr,
                                              unsigned short* __restrict__ csr_row_c,
                                              unsigned short* __restrict__ csr_col_r,
                                              float* __restrict__ Binv,
                                              float* __restrict__ dinv) {
  const int side = blockIdx.x >= NB ? 1 : 0;
  const int b = blockIdx.x - side * NB;
  const int* tmp = side ? tmp_c : tmp_r;
  const int* bs = side ? bs_c : bs_r;
  int* ptr = side ? cptr : rptr;
  unsigned short* csr = side ? csr_col_r : csr_row_c;

  const int base = bs[b];
  const int M = bs[b + 1] - base;
  __shared__ int cnt[128], pre[128], cur[128];
  __shared__ float ds[128];
  const int t = threadIdx.x;
  if (t < 128) { cnt[t] = 0; ds[t] = 0.f; }
  __syncthreads();
  for (int i = t; i < M; i += 256) atomicAdd(cnt + (tmp[base + i] >> 16), 1);
  __syncthreads();
  if (t < 128) pre[t] = cnt[t];
  __syncthreads();
  for (int off = 1; off < 128; off <<= 1) {
    int u = (t >= off && t < 128) ? pre[t - off] : 0;
    __syncthreads();
    if (t < 128) pre[t] += u;
    __syncthreads();
  }
  const int node0 = b << 7;
  if (t < 128) {
    int excl = pre[t] - cnt[t];
    int g = node0 + t;
    if (g <= NN) ptr[g] = base + excl;
    cur[t] = base + excl;
    if (side && g < NN) Binv[g] = cnt[t] > 0 ? hw[g] / (float)cnt[t] : 0.f;
  }
  __syncthreads();
  for (int i = t; i < M; i += 256) {
    int e = tmp[base + i];
    int own = e >> 16;
    int other = e & 0xFFFF;
    int pos = atomicAdd(cur + own, 1);
    csr[pos] = (unsigned short)other;
    if (!side) atomicAdd(ds + own, hw[other]);
  }
  __syncthreads();
  if (!side && t < 128) {
    int g = node0 + t;
    if (g < NN) dinv[g] = ds[t] > 0.f ? 1.0f / ds[t] : 0.f;
  }
}

// ---------------------------------------------------------------------------
// GEMM1 on matrix cores: xh16[N][64] (bf16) = bf16(x[N][512]) @ bf16(W1).
// Block = 64 rows, 4 waves; wave w computes rows 16w..16w+15 (all 64 cols).
// mfma_f32_16x16x32_bf16; fragment layouts per guide §3 (m89-verified):
//   A: row=lane&15, k=(lane>>4)*8+i ; B: col=lane&15, same k
//   C/D: col=lane&15, row=(lane>>4)*4+reg
__global__ __launch_bounds__(256) void gemm1_mfma(const float* __restrict__ x,
                                                  const unsigned short* __restrict__ w1t,
                                                  unsigned short* __restrict__ xh16) {
  __shared__ unsigned short lxA[64][40];  // [row][k] bf16, pad 40 (80B rows: aligned, 2-way banks)
  __shared__ unsigned short lwB[64][40];  // [col][k] bf16
  const int t = threadIdx.x;
  const int w = t >> 6;
  const int lane = t & 63;
  const int row0 = blockIdx.x * 64;
  // staging mappings (one 32-B f32 read -> 16-B bf16 LDS write per thread for x;
  // one 16-B bf16 read -> 16-B LDS write for W)
  const int sr = t >> 2;            // 0..63
  const int sk = (t & 3) * 8;       // 0,8,16,24
  // fragment address components
  const int fr = lane & 15;
  const int fk = (lane >> 4) * 8;

  f32x4 acc[4] = {f32x4{0.f, 0.f, 0.f, 0.f}, f32x4{0.f, 0.f, 0.f, 0.f},
                  f32x4{0.f, 0.f, 0.f, 0.f}, f32x4{0.f, 0.f, 0.f, 0.f}};

  for (int kb = 0; kb < FIN; kb += 32) {
    // stage x (f32 -> bf16)
    {
      int grow = row0 + sr;
      float4 a0 = make_float4(0.f, 0.f, 0.f, 0.f), a1 = a0;
      if (grow < NN) {
        const float4* p = reinterpret_cast<const float4*>(x + (size_t)grow * FIN + kb + sk);
        a0 = p[0]; a1 = p[1];
      }
      uint4 packed;
      packed.x = (unsigned int)f2bf(a0.x) | ((unsigned int)f2bf(a0.y) << 16);
      packed.y = (unsigned int)f2bf(a0.z) | ((unsigned int)f2bf(a0.w) << 16);
      packed.z = (unsigned int)f2bf(a1.x) | ((unsigned int)f2bf(a1.y) << 16);
      packed.w = (unsigned int)f2bf(a1.z) | ((unsigned int)f2bf(a1.w) << 16);
      *reinterpret_cast<uint4*>(&lxA[sr][sk]) = packed;
    }
    // stage W (already bf16, transposed [col][k])
    {
      const uint4* q = reinterpret_cast<const uint4*>(w1t + (size_t)sr * FIN + kb + sk);
      *reinterpret_cast<uint4*>(&lwB[sr][sk]) = q[0];
    }
    __syncthreads();
    bf16x8 afrag = *reinterpret_cast<const bf16x8*>(&lxA[16 * w + fr][fk]);
#pragma unroll
    for (int b = 0; b < 4; ++b) {
      bf16x8 bfrag = *reinterpret_cast<const bf16x8*>(&lwB[16 * b + fr][fk]);
      acc[b] = __builtin_amdgcn_mfma_f32_16x16x32_bf16(afrag, bfrag, acc[b], 0, 0, 0);
    }
    __syncthreads();
  }
  // write C as bf16: row = 16w + (lane>>4)*4 + v, col = 16b + (lane&15)
  const int crow0 = row0 + 16 * w + (lane >> 4) * 4;
#pragma unroll
  for (int v = 0; v < 4; ++v) {
    int gr = crow0 + v;
    if (gr < NN) {
#pragma unroll
      for (int b = 0; b < 4; ++b)
        xh16[(size_t)gr * HID + 16 * b + fr] = f2bf(acc[b][v]);
    }
  }
}

// ---------------------------------------------------------------------------
// Attention projections from bf16 xh: sird.x = s_i*log2e, s_j = s_j*log2e.
__global__ __launch_bounds__(256) void attscore_kernel(const unsigned short* __restrict__ xh16,
                                                       const float* __restrict__ att1,
                                                       float2* __restrict__ sird,
                                                       float* __restrict__ s_j) {
  int t = blockIdx.x * 256 + threadIdx.x;
  if (t >= NN * NHEAD) return;
  int hh = t & 7;
  const size_t base = (size_t)t * 8;
  uint4 p = *reinterpret_cast<const uint4*>(xh16 + base);
  float v[8];
  v[0] = bf2f((unsigned short)(p.x & 0xFFFF)); v[1] = bf2f((unsigned short)(p.x >> 16));
  v[2] = bf2f((unsigned short)(p.y & 0xFFFF)); v[3] = bf2f((unsigned short)(p.y >> 16));
  v[4] = bf2f((unsigned short)(p.z & 0xFFFF)); v[5] = bf2f((unsigned short)(p.z >> 16));
  v[6] = bf2f((unsigned short)(p.w & 0xFFFF)); v[7] = bf2f((unsigned short)(p.w >> 16));
  float si = 0.f, sj = 0.f;
#pragma unroll
  for (int c = 0; c < OUT1; ++c) {
    si = fmaf(v[c], att1[hh * 16 + c], si);
    sj = fmaf(v[c], att1[hh * 16 + 8 + c], sj);
  }
  sird[t] = make_float2(si * LOG2E, 0.f);
  s_j[t] = sj * LOG2E;
}

// ---------------------------------------------------------------------------
// Softmax denominator (reciprocal -> sird.y).
__global__ __launch_bounds__(256) void den_csr(const int* __restrict__ rptr,
                                               const unsigned short* __restrict__ csr_row_c,
                                               const float* __restrict__ s_j,
                                               float2* __restrict__ sird) {
  int wid = (blockIdx.x * 256 + threadIdx.x) >> 6;
  int lane = threadIdx.x & 63;
  if (wid >= NN) return;
  int r = wid;
  int hh = lane & 7;
  int eslot = lane >> 3;
  float si = sird[r * 8 + hh].x;
  int beg = rptr[r], end = rptr[r + 1];
  float aexp = 0.f;
  int i = beg + eslot;
  for (; i + 8 < end; i += 16) {
    int c0 = csr_row_c[i], c1 = csr_row_c[i + 8];
    float sj0 = s_j[c0 * 8 + hh], sj1 = s_j[c1 * 8 + hh];
    float a0 = LRELU(si + sj0), a1 = LRELU(si + sj1);
    aexp += fexp2(a0) + fexp2(a1);
  }
  if (i < end) {
    int c = csr_row_c[i];
    float a = LRELU(si + s_j[c * 8 + hh]);
    aexp += fexp2(a);
  }
  aexp += __shfl_xor(aexp, 8);
  aexp += __shfl_xor(aexp, 16);
  aexp += __shfl_xor(aexp, 32);
  if (eslot == 0)
    reinterpret_cast<float*>(sird)[(r * 8 + hh) * 2 + 1] = 1.0f / (aexp + 1e-16f);
}

// ---------------------------------------------------------------------------
// Propagate 1 (nodes -> hyperedges): wave per hyperedge c, lane = channel.
// bf16 payload gathers (128B/row), f32 accumulation, bf16 output.
__global__ __launch_bounds__(256) void prop1_csr(const int* __restrict__ cptr,
                                                 const unsigned short* __restrict__ csr_col_r,
                                                 const unsigned short* __restrict__ xh16,
                                                 const float2* __restrict__ sird,
                                                 const float* __restrict__ s_j,
                                                 const float* __restrict__ Binv,
                                                 unsigned short* __restrict__ acc_e16) {
  int wid = (blockIdx.x * 256 + threadIdx.x) >> 6;
  int lane = threadIdx.x & 63;
  if (wid >= NN) return;
  const int c = wid;
  const int hh = lane >> 3;
  const int j = lane & 7;
  const int abase = lane & 56;
  float sj = s_j[c * 8 + hh];
  int beg = cptr[c], end = cptr[c + 1];
  float acc = 0.f;
  int i = beg;
  for (; i + 16 <= end; i += 16) {
    int r0 = csr_col_r[i + j];
    int r1 = csr_col_r[i + 8 + j];
    float2 q0 = sird[r0 * 8 + hh];
    float2 q1 = sird[r1 * 8 + hh];
    unsigned short va[8], vb[8];
#pragma unroll
    for (int j2 = 0; j2 < 8; ++j2)
      va[j2] = xh16[(__shfl(r0, j2) << 6) + lane];
#pragma unroll
    for (int j2 = 0; j2 < 8; ++j2)
      vb[j2] = xh16[(__shfl(r1, j2) << 6) + lane];
    float a0 = fexp2(LRELU(q0.x + sj)) * q0.y;
    float a1 = fexp2(LRELU(q1.x + sj)) * q1.y;
#pragma unroll
    for (int j2 = 0; j2 < 8; ++j2)
      acc = fmaf(bf2f(va[j2]), __shfl(a0, abase + j2), acc);
#pragma unroll
    for (int j2 = 0; j2 < 8; ++j2)
      acc = fmaf(bf2f(vb[j2]), __shfl(a1, abase + j2), acc);
  }
  for (; i + 8 <= end; i += 8) {
    int rj = csr_col_r[i + j];
    float2 q = sird[rj * 8 + hh];
    unsigned short va[8];
#pragma unroll
    for (int j2 = 0; j2 < 8; ++j2)
      va[j2] = xh16[(__shfl(rj, j2) << 6) + lane];
    float aexp = fexp2(LRELU(q.x + sj)) * q.y;
#pragma unroll
    for (int j2 = 0; j2 < 8; ++j2)
      acc = fmaf(bf2f(va[j2]), __shfl(aexp, abase + j2), acc);
  }
  for (; i < end; ++i) {
    int r = csr_col_r[i];
    float2 q = sird[r * 8 + hh];
    float a = LRELU(q.x + sj);
    acc = fmaf(bf2f(xh16[(r << 6) + lane]), fexp2(a) * q.y, acc);
  }
  acc_e16[(c << 6) + lane] = f2bf(acc * Binv[c]);
}

// ---------------------------------------------------------------------------
// Propagate 2 (hyperedges -> nodes) + finish1: wave per node r.
__global__ __launch_bounds__(256) void prop2_csr(const int* __restrict__ rptr,
                                                 const unsigned short* __restrict__ csr_row_c,
                                                 const unsigned short* __restrict__ acc_e16,
                                                 const float2* __restrict__ sird,
                                                 const float* __restrict__ s_j,
                                                 const float* __restrict__ dinv,
                                                 const float* __restrict__ b1,
                                                 float* __restrict__ h) {
  int wid = (blockIdx.x * 256 + threadIdx.x) >> 6;
  int lane = threadIdx.x & 63;
  if (wid >= NN) return;
  const int r = wid;
  const int hh = lane >> 3;
  const int j = lane & 7;
  const int abase = lane & 56;
  float2 sr = sird[r * 8 + hh];
  const float si = sr.x, rd = sr.y;
  int beg = rptr[r], end = rptr[r + 1];
  float acc = 0.f;
  int i = beg;
  for (; i + 16 <= end; i += 16) {
    int c0 = csr_row_c[i + j];
    int c1 = csr_row_c[i + 8 + j];
    float sj0 = s_j[c0 * 8 + hh];
    float sj1 = s_j[c1 * 8 + hh];
    unsigned short va[8], vb[8];
#pragma unroll
    for (int j2 = 0; j2 < 8; ++j2)
      va[j2] = acc_e16[(__shfl(c0, j2) << 6) + lane];
#pragma unroll
    for (int j2 = 0; j2 < 8; ++j2)
      vb[j2] = acc_e16[(__shfl(c1, j2) << 6) + lane];
    float a0 = fexp2(LRELU(si + sj0));
    float a1 = fexp2(LRELU(si + sj1));
#pragma unroll
    for (int j2 = 0; j2 < 8; ++j2)
      acc = fmaf(bf2f(va[j2]), __shfl(a0, abase + j2), acc);
#pragma unroll
    for (int j2 = 0; j2 < 8; ++j2)
      acc = fmaf(bf2f(vb[j2]), __shfl(a1, abase + j2), acc);
  }
  for (; i + 8 <= end; i += 8) {
    int cj = csr_row_c[i + j];
    float sjv = s_j[cj * 8 + hh];
    unsigned short va[8];
#pragma unroll
    for (int j2 = 0; j2 < 8; ++j2)
      va[j2] = acc_e16[(__shfl(cj, j2) << 6) + lane];
    float aexp = fexp2(LRELU(si + sjv));
#pragma unroll
    for (int j2 = 0; j2 < 8; ++j2)
      acc = fmaf(bf2f(va[j2]), __shfl(aexp, abase + j2), acc);
  }
  for (; i < end; ++i) {
    int cc = csr_row_c[i];
    float aexp = fexp2(LRELU(si + s_j[cc * 8 + hh]));
    acc = fmaf(bf2f(acc_e16[(cc << 6) + lane]), aexp, acc);
  }
  acc *= rd;
  float v = fmaf(acc, dinv[r], b1[lane]);
  h[(r << 6) + lane] = v > 0.f ? v : expm1f(v);
}

// ---------------------------------------------------------------------------
// GEMM2: xh2[n,k] = sum_c h[n,c]*W2[c,k]  (k<7; slot 7 zeroed)
__global__ __launch_bounds__(256) void gemm2_kernel(const float* __restrict__ h,
                                                    const float* __restrict__ W2,
                                                    float* __restrict__ xh2) {
  int t = blockIdx.x * 256 + threadIdx.x;
  if (t >= NN * 8) return;
  int n = t >> 3, k = t & 7;
  if (k == 7) { xh2[t] = 0.f; return; }
  const float* hp = h + (size_t)n * HID;
  float acc = 0.f;
#pragma unroll
  for (int c = 0; c < HID; ++c) acc = fmaf(hp[c], W2[c * NCLS + k], acc);
  xh2[t] = acc;
}

// ---------------------------------------------------------------------------
// Layer-2 propagate 1: acc_e2[g] = Binv[g] * sum_r xh2[r]
__global__ __launch_bounds__(256) void prop3_csr(const int* __restrict__ cptr,
                                                 const unsigned short* __restrict__ csr_col_r,
                                                 const float* __restrict__ xh2,
                                                 const float* __restrict__ Binv,
                                                 float* __restrict__ acc_e2) {
  int t = blockIdx.x * 256 + threadIdx.x;
  int g = t >> 3, k = t & 7;
  if (g >= NN) return;
  int beg = cptr[g], end = cptr[g + 1];
  float acc = 0.f;
  int i = beg;
  for (; i + 3 < end; i += 4) {
    int r0 = csr_col_r[i], r1 = csr_col_r[i + 1];
    int r2 = csr_col_r[i + 2], r3 = csr_col_r[i + 3];
    float v0 = xh2[r0 * 8 + k], v1 = xh2[r1 * 8 + k];
    float v2 = xh2[r2 * 8 + k], v3 = xh2[r3 * 8 + k];
    acc += (v0 + v1) + (v2 + v3);
  }
  for (; i < end; ++i) acc += xh2[csr_col_r[i] * 8 + k];
  acc_e2[g * 8 + k] = acc * Binv[g];
}

// ---------------------------------------------------------------------------
// Layer-2 propagate 2 + log_softmax: 8 lanes per node.
__global__ __launch_bounds__(256) void prop4_csr(const int* __restrict__ rptr,
                                                 const unsigned short* __restrict__ csr_row_c,
                                                 const float* __restrict__ acc_e2,
                                                 const float* __restrict__ dinv,
                                                 const float* __restrict__ b2,
                                                 float* __restrict__ out) {
  int t = blockIdx.x * 256 + threadIdx.x;
  int r = t >> 3, k = t & 7;
  if (r >= NN) return;
  int beg = rptr[r], end = rptr[r + 1];
  float acc = 0.f;
  int i = beg;
  for (; i + 3 < end; i += 4) {
    int c0 = csr_row_c[i], c1 = csr_row_c[i + 1];
    int c2 = csr_row_c[i + 2], c3 = csr_row_c[i + 3];
    float v0 = acc_e2[c0 * 8 + k], v1 = acc_e2[c1 * 8 + k];
    float v2 = acc_e2[c2 * 8 + k], v3 = acc_e2[c3 * 8 + k];
    acc += (v0 + v1) + (v2 + v3);
  }
  for (; i < end; ++i) acc += acc_e2[csr_row_c[i] * 8 + k];
  float v = (k < NCLS) ? fmaf(acc, dinv[r], b2[k]) : -INFINITY;
  float m = v;
  m = fmaxf(m, __shfl_xor(m, 1, 8));
  m = fmaxf(m, __shfl_xor(m, 2, 8));
  m = fmaxf(m, __shfl_xor(m, 4, 8));
  float ex = (k < NCLS) ? expf(v - m) : 0.f;
  float s = ex;
  s += __shfl_xor(s, 1, 8);
  s += __shfl_xor(s, 2, 8);
  s += __shfl_xor(s, 4, 8);
  float lse = m + logf(s);
  if (k < NCLS) out[(size_t)r * NCLS + k] = v - lse;
}

// ---------------------------------------------------------------------------
extern "C" void kernel_launch(void* const* d_in, const int* in_sizes, int n_in,
                              void* d_out, int out_size, void* d_ws, size_t ws_size,
                              hipStream_t stream) {
  const float* x    = (const float*)d_in[0];
  const int*   ei   = (const int*)d_in[1];
  const float* hw   = (const float*)d_in[2];
  const float* W1   = (const float*)d_in[3];
  const float* att1 = (const float*)d_in[4];
  const float* b1   = (const float*)d_in[5];
  const float* W2   = (const float*)d_in[6];
  const float* b2   = (const float*)d_in[7];
  float* out = (float*)d_out;
  float* ws  = (float*)d_ws;

  float* s_j    = ws + OFF_SJ;
  float2* sird  = (float2*)(ws + OFF_SIRD);
  float* dinv   = ws + OFF_DINV;
  float* Binv   = ws + OFF_BINV;
  unsigned short* xh16    = (unsigned short*)(ws + OFF_XH16);
  unsigned short* acc_e16 = (unsigned short*)(ws + OFF_ACCE16);
  float* hbuf   = ws + OFF_H;      // W1T16 lives here until prop2 writes h
  unsigned short* w1t = (unsigned short*)(ws + OFF_H);
  float* xh2    = ws + OFF_XH2;
  float* acc_e2 = ws + OFF_ACCE2;
  int* rptr = (int*)(ws + OFF_RPTR);
  int* cptr = (int*)(ws + OFF_CPTR);
  int* bh_r = (int*)(ws + OFF_BHR);
  int* bh_c = (int*)(ws + OFF_BHC);
  int* bs_r = (int*)(ws + OFF_BSR);
  int* bs_c = (int*)(ws + OFF_BSC);
  int* bc_r = (int*)(ws + OFF_BCR);
  int* bc_c = (int*)(ws + OFF_BCC);
  unsigned short* csr_row_c = (unsigned short*)(ws + OFF_CSRRC);
  unsigned short* csr_col_r = (unsigned short*)(ws + OFF_CSRCR);
  int* tmp_r = (int*)(ws + OFF_P0);    // aliases free region (consumed by phaseB)
  int* tmp_c = (int*)(ws + OFF_XH16);  // aliases xh16 region (consumed by phaseB)

  // --- CSR build (bucketed counting sort, both orderings) + W1 prep ---
  zero_small<<<1, 512, 0, stream>>>(bh_r, bh_c);
  wconv_kernel<<<(FIN * HID + 255) / 256, 256, 0, stream>>>(W1, w1t);
  bucket_hist<<<256, 256, 0, stream>>>(ei, bh_r, bh_c);
  bucket_scan<<<1, 512, 0, stream>>>(bh_r, bh_c, bs_r, bs_c, bc_r, bc_c);
  phaseA<<<(EE + EPB - 1) / EPB, 256, 0, stream>>>(ei, bc_r, bc_c, tmp_r, tmp_c);
  phaseB<<<2 * NB, 256, 0, stream>>>(tmp_r, tmp_c, bs_r, bs_c, hw,
                                     rptr, cptr, csr_row_c, csr_col_r, Binv, dinv);

  // --- Layer 1 ---
  gemm1_mfma<<<(NN + 63) / 64, 256, 0, stream>>>(x, w1t, xh16);
  attscore_kernel<<<(NN * NHEAD + 255) / 256, 256, 0, stream>>>(xh16, att1, sird, s_j);
  den_csr<<<(NN * 64 + 255) / 256, 256, 0, stream>>>(rptr, csr_row_c, s_j, sird);
  prop1_csr<<<(NN * 64 + 255) / 256, 256, 0, stream>>>(cptr, csr_col_r, xh16, sird,
                                                       s_j, Binv, acc_e16);
  prop2_csr<<<(NN * 64 + 255) / 256, 256, 0, stream>>>(rptr, csr_row_c, acc_e16, sird,
                                                       s_j, dinv, b1, hbuf);

  // --- Layer 2 ---
  gemm2_kernel<<<(NN * 8 + 255) / 256, 256, 0, stream>>>(hbuf, W2, xh2);
  prop3_csr<<<(NN * 8 + 255) / 256, 256, 0, stream>>>(cptr, csr_col_r, xh2, Binv, acc_e2);
  prop4_csr<<<(NN * 8 + 255) / 256, 256, 0, stream>>>(rptr, csr_row_c, acc_e2, dinv, b2, out);
}